// Round 8
// baseline (144.880 us; speedup 1.0000x reference)
//
#include <hip/hip_runtime.h>
#include <hip/hip_bf16.h>

// out[b] = SCALE*query[b]@P[b] + row[b]
//   M  = Wc1^T + prev@Wc2^T            (Mt = M^T, fp32+bf16)
//   Tt[b] = NT(Mt, keyzT[b])           (T = keyz^T@M; keyz = key rows zeroed by mask)
//   W2 = Wq^T@Wk,  u = Wq^T bk,  w3 = Wk^T bq
//   Pt[b] = NT(Tt[b], W2) + s1[b][d2]*u[d0]     (rank-1 bk-term folded in epilogue)
//   s1[b][d]  = sum_{mask=1} M[k][d],  sm0 = sum_{mask=0} M[k][d]
//   row[b][d] = bc[d] - 1e9*sm0[b][d] + SCALE*(w3@T[b] + (bq.bk)*s1[b][d])
//   G5: out = SCALE*NT(query, Pt) + row — query fp32 reg-staged + packed to the
//       PROVEN bf16 rotation LDS layout (fp32-in-LDS measured 2.36M conflicts, r7).
// NT GEMMs: bf16 MFMA 16x16x32, BK=64, global_load_lds(16B), rotation LDS
// swizzle g'=(g+row)&7 (measured 0 conflicts), bijective XCD swizzle,
// single-buffer 2-barrier schedule (explicit gload-dbuf regressed, r6).

typedef __attribute__((ext_vector_type(8))) short short8;
typedef __attribute__((ext_vector_type(4))) float f32x4;
typedef __attribute__((ext_vector_type(4))) unsigned int u32x4;

#define SCALE 0.03608439182435161f   /* 1/sqrt(768) */

__device__ inline unsigned short f2bf(float x) {
  unsigned int u = __builtin_bit_cast(unsigned int, x);
  u = (u + 0x7fffu + ((u >> 16) & 1u)) >> 16;   // RNE
  return (unsigned short)u;
}
__device__ inline float bf2f(unsigned short h) {
  return __builtin_bit_cast(float, ((unsigned int)h) << 16);
}
__device__ inline unsigned int pack_trunc(float hi, float lo) {
  // {bf16(lo) | bf16(hi)<<16} via one v_perm (truncation; data path only)
  return __builtin_amdgcn_perm(__builtin_bit_cast(unsigned int, hi),
                               __builtin_bit_cast(unsigned int, lo), 0x07060302u);
}

// ---------------- prep kernels ----------------
// region 0: prev cvt, region 1: Wc2 slice cvt
__global__ void k_prep(const float* __restrict__ prev, const float* __restrict__ Wc,
                       unsigned short* __restrict__ prev_bf,
                       unsigned short* __restrict__ Wc2_bf) {
  int g = blockIdx.x;
  int region = g / 576;
  int idx = (g - region * 576) * 256 + threadIdx.x;       // < 147456 float4-groups
  float4 v;
  unsigned short* dst;
  if (region == 0) { v = reinterpret_cast<const float4*>(prev)[idx]; dst = prev_bf; }
  else {
    int r = idx / 192, c4 = (idx - r * 192) * 4;
    v = *reinterpret_cast<const float4*>(Wc + (long long)r * 1536 + 768 + c4);
    dst = Wc2_bf;
  }
  reinterpret_cast<ushort4*>(dst)[idx] = make_ushort4(f2bf(v.x), f2bf(v.y), f2bf(v.z), f2bf(v.w));
}

// z=0: WqT = Wq^T;  z=1: WkT = Wk^T  (LDS-tiled, bf16 out)
__global__ void k_tposeW(const float* __restrict__ Wq, const float* __restrict__ Wk,
                         unsigned short* __restrict__ WqT, unsigned short* __restrict__ WkT) {
  __shared__ float t[64][65];
  const float* src = blockIdx.z ? Wk : Wq;
  unsigned short* dst = blockIdx.z ? WkT : WqT;
  int bx = blockIdx.x * 64, by = blockIdx.y * 64;
  int tx = threadIdx.x & 63, ty = threadIdx.x >> 6;
  #pragma unroll
  for (int i = 0; i < 64; i += 4)
    t[ty + i][tx] = src[(long long)(by + ty + i) * 768 + bx + tx];
  __syncthreads();
  #pragma unroll
  for (int i = 0; i < 64; i += 4)
    dst[(long long)(bx + ty + i) * 768 + by + tx] = f2bf(t[tx][ty + i]);
}

// keyzT[b][d1][k] = f2bf(mask[b][k] ? key[b][k][d1] : 0)
__global__ void k_cvtz(const float* __restrict__ key, const int* __restrict__ mask,
                       unsigned short* __restrict__ keyzT) {
  __shared__ float t[64][65];
  int b = blockIdx.z;
  const float* src = key + (long long)b * 589824;
  unsigned short* dst = keyzT + (long long)b * 589824;
  const int* mb = mask + b * 768;
  int bx = blockIdx.x * 64, by = blockIdx.y * 64;   // by+r = k, bx+c = d1
  int tx = threadIdx.x & 63, ty = threadIdx.x >> 6;
  #pragma unroll
  for (int i = 0; i < 64; i += 4) {
    float v = src[(long long)(by + ty + i) * 768 + bx + tx];
    t[ty + i][tx] = mb[by + ty + i] ? v : 0.0f;
  }
  __syncthreads();
  #pragma unroll
  for (int i = 0; i < 64; i += 4)
    dst[(long long)(bx + ty + i) * 768 + by + tx] = f2bf(t[tx][ty + i]);
}

// u[d0] = sum_j WqT[d0][j]*bk[j];  w3[d1] = sum_j WkT[d1][j]*bq[j]
__global__ void k_scalars(const unsigned short* __restrict__ WqT,
                          const unsigned short* __restrict__ WkT,
                          const float* __restrict__ bk, const float* __restrict__ bq,
                          float* __restrict__ u, float* __restrict__ w3) {
  int gw = blockIdx.x * 4 + (threadIdx.x >> 6);
  int lane = threadIdx.x & 63;
  if (gw >= 1536) return;
  const unsigned short* wrow = (gw < 768) ? (WqT + (long long)gw * 768)
                                          : (WkT + (long long)(gw - 768) * 768);
  const float* vec = (gw < 768) ? bk : bq;
  float s = 0.f;
  for (int j = lane; j < 768; j += 64) s += bf2f(wrow[j]) * vec[j];
  #pragma unroll
  for (int off = 32; off > 0; off >>= 1) s += __shfl_down(s, off, 64);
  if (lane == 0) { if (gw < 768) u[gw] = s; else w3[gw - 768] = s; }
}

// s1[b][d2]=sum_{mask=1}Mt[d2][k]; sm0[b][d2]=sum_{mask=0}Mt[d2][k]  (fp32)
__global__ void k_scol(const float* __restrict__ Mt, const int* __restrict__ mask,
                       float* __restrict__ s1, float* __restrict__ sm0) {
  int gw = blockIdx.x * 4 + (threadIdx.x >> 6);
  int lane = threadIdx.x & 63;
  int b = gw / 768, d2 = gw - b * 768;
  if (b >= 8) return;
  const int* mb = mask + b * 768;
  const float* mrow = Mt + (long long)d2 * 768;
  float a1 = 0.f, a0 = 0.f;
  for (int k = lane; k < 768; k += 64) {
    float v = mrow[k];
    if (mb[k]) a1 += v; else a0 += v;
  }
  #pragma unroll
  for (int off = 32; off > 0; off >>= 1) {
    a1 += __shfl_down(a1, off, 64);
    a0 += __shfl_down(a0, off, 64);
  }
  if (lane == 0) { s1[gw] = a1; sm0[gw] = a0; }
}

// row[b][d2] = bc - 1e9*sm0 + SCALE*(sum_d1 Tt[b][d2][d1]*w3[d1] + (bq.bk)*s1)
__global__ void k_row(const unsigned short* __restrict__ Tt, const float* __restrict__ w3,
                      const float* __restrict__ s1, const float* __restrict__ sm0,
                      const float* __restrict__ bq, const float* __restrict__ bk,
                      const float* __restrict__ bc, float* __restrict__ row) {
  int gw = blockIdx.x * 4 + (threadIdx.x >> 6);
  int lane = threadIdx.x & 63;
  int b = gw / 768, d2 = gw - b * 768;
  if (b >= 8) return;
  const unsigned short* trow = Tt + ((long long)b * 768 + d2) * 768;
  float st = 0.f, sbb = 0.f;
  for (int j = lane; j < 768; j += 64) {
    st += bf2f(trow[j]) * w3[j];
    sbb += bq[j] * bk[j];
  }
  #pragma unroll
  for (int off = 32; off > 0; off >>= 1) {
    st += __shfl_down(st, off, 64);
    sbb += __shfl_down(sbb, off, 64);
  }
  if (lane == 0)
    row[gw] = bc[d2] - 1e9f * sm0[gw] + SCALE * (st + sbb * s1[gw]);
}

// ---------------- NT GEMM: C[m][n] = sum_k A[m][k]*B[n][k], K=768, BK=64 ----------
// MODE 0: Mt fp32+bf16 = acc + Wc1[m][n] (aux=Wc ld1536)
// MODE 2: bf16 = acc
// MODE 4: out fp32 = SCALE*acc + aux[b*768+n]              (row add)
// MODE 5: bf16 = acc + aux[b*768+m]*aux2[n]                (rank-1 fold)
// AREG=1 (BM=128 only): A is fp32; reg-staged (8x dwordx4 issued before compute,
//   v_perm-packed to bf16, ds_write_b128 into the rotation layout after barrier).
template <int MODE, int BM, int BN, int AREG>
__global__ __launch_bounds__(256) void gemm_nt(
    const void* __restrict__ A, long long aStr, int lda,
    const unsigned short* __restrict__ B, long long bStr, int ldb,
    float* __restrict__ Cf, unsigned short* __restrict__ Cbf,
    long long cStr, int ldc,
    const float* __restrict__ aux, const float* __restrict__ aux2)
{
  constexpr int BK = 64;
  constexpr int MI = BM / 32, NJ = BN / 32;
  constexpr int AGT = BM * 8 / 256, BGT = BN * 8 / 256;
  __shared__ __align__(16) char As[BM * BK * 2];
  __shared__ __align__(16) char Bs[BN * BK * 2];

  // bijective XCD swizzle (m204)
  const int gx = gridDim.x, gy = gridDim.y;
  const int nwg = gx * gy * (int)gridDim.z;
  int lin = blockIdx.x + gx * (blockIdx.y + gy * blockIdx.z);
  int qq = nwg >> 3, rr = nwg & 7, xcd = lin & 7, loc = lin >> 3;
  int swz = (xcd < rr ? xcd * (qq + 1) : rr * (qq + 1) + (xcd - rr) * qq) + loc;
  int bz = swz / (gx * gy);
  int rem = swz - bz * gx * gy;
  int by = rem / gx, bx = rem - by * gx;

  const int b = bz;
  const int m0 = by * BM, n0 = bx * BN;
  const unsigned short* Bb = B + (long long)b * bStr;

  const int tid = threadIdx.x;
  const int w = tid >> 6, lane = tid & 63;
  const int wr = w >> 1, wc = w & 1;       // 2x2 waves
  const int fr = lane & 15, fq = lane >> 4;

  f32x4 acc[MI][NJ] = {};

  // ---- A staging machinery ----
  const unsigned short* Ab16 = (const unsigned short*)A + (AREG ? 0 : (long long)b * aStr);
  const float*          Abf  = (const float*)A + (AREG ? (long long)b * aStr : 0);
  const int arow = tid >> 1, ahalf = tid & 1;    // AREG: 128 rows x 2 half-rows
  f32x4 areg[8];

  auto loadA = [&](int kt) {       // AREG only: issue 8 dwordx4 (128B of query fp32)
    const float* src = Abf + (long long)(m0 + arow) * lda + kt + ahalf * 32;
    #pragma unroll
    for (int j = 0; j < 8; ++j)
      areg[j] = *reinterpret_cast<const f32x4*>(src + j * 4);
  };
  auto packWriteA = [&]() {        // AREG only: pack -> rotation-layout bf16 LDS
    #pragma unroll
    for (int jj = 0; jj < 4; ++jj) {
      f32x4 x = areg[2 * jj], y = areg[2 * jj + 1];
      u32x4 u4 = {pack_trunc(x[1], x[0]), pack_trunc(x[3], x[2]),
                  pack_trunc(y[1], y[0]), pack_trunc(y[3], y[2])};
      int c = ahalf * 4 + jj;
      int g = arow * 8 + ((c + arow) & 7);
      *reinterpret_cast<short8*>(As + g * 16) = __builtin_bit_cast(short8, u4);
    }
  };
  auto gloadA = [&](int kt) {      // bf16 A path: linear dest, inverse-rotated source
    #pragma unroll
    for (int t = 0; t < AGT; ++t) {
      int g = t * 256 + tid;
      int row = g >> 3, s = g & 7;
      int sg = (s - row) & 7;
      const unsigned short* ga = Ab16 + (long long)(m0 + row) * lda + kt + sg * 8;
      __builtin_amdgcn_global_load_lds(
          (const __attribute__((address_space(1))) void*)ga,
          (__attribute__((address_space(3))) void*)(As + g * 16), 16, 0, 0);
    }
  };
  auto gloadB = [&](int kt) {
    #pragma unroll
    for (int t = 0; t < BGT; ++t) {
      int g = t * 256 + tid;
      int row = g >> 3, s = g & 7;
      int sg = (s - row) & 7;
      const unsigned short* gb = Bb + (long long)(n0 + row) * ldb + kt + sg * 8;
      __builtin_amdgcn_global_load_lds(
          (const __attribute__((address_space(1))) void*)gb,
          (__attribute__((address_space(3))) void*)(Bs + g * 16), 16, 0, 0);
    }
  };
  auto compute = [&]() {
    #pragma unroll
    for (int kk = 0; kk < 2; ++kk) {
      short8 af[MI], bfr[NJ];
      #pragma unroll
      for (int i = 0; i < MI; ++i) {
        int r = wr * (BM / 2) + i * 16 + fr;
        int sgi = ((kk * 4 + fq) + r) & 7;          // rotation-swizzled granule
        af[i] = *reinterpret_cast<const short8*>(As + r * 128 + sgi * 16);
      }
      #pragma unroll
      for (int j = 0; j < NJ; ++j) {
        int r = wc * (BN / 2) + j * 16 + fr;
        int sgj = ((kk * 4 + fq) + r) & 7;
        bfr[j] = *reinterpret_cast<const short8*>(Bs + r * 128 + sgj * 16);
      }
      #pragma unroll
      for (int i = 0; i < MI; ++i)
        #pragma unroll
        for (int j = 0; j < NJ; ++j)
          acc[i][j] = __builtin_amdgcn_mfma_f32_16x16x32_bf16(af[i], bfr[j], acc[i][j], 0, 0, 0);
    }
  };

  if constexpr (AREG) {
    // prologue: stage tile 0 (B via gload_lds, A via reg-pack)
    gloadB(0);
    loadA(0);
    packWriteA();
    __syncthreads();
    for (int t = 0; t < 12; ++t) {
      if (t < 11) loadA((t + 1) * BK);   // prefetch into regs; hides under MFMA
      compute();
      __syncthreads();                   // all waves done reading As/Bs
      if (t < 11) {
        gloadB((t + 1) * BK);
        packWriteA();                    // waits only its own reg loads
        __syncthreads();                 // stage visible
      }
    }
  } else {
    for (int kt = 0; kt < 768; kt += BK) {
      __syncthreads();
      gloadA(kt);
      gloadB(kt);
      __syncthreads();
      compute();
    }
  }

  #pragma unroll
  for (int i = 0; i < MI; ++i)
    #pragma unroll
    for (int j = 0; j < NJ; ++j)
      #pragma unroll
      for (int r = 0; r < 4; ++r) {
        int row = m0 + wr * (BM / 2) + i * 16 + fq * 4 + r;  // C/D: col=lane&15, row=(lane>>4)*4+r
        int col = n0 + wc * (BN / 2) + j * 16 + fr;
        float v = acc[i][j][r];
        if constexpr (MODE == 0) {
          v += aux[(long long)row * 1536 + col];       // + Wc1[d2][k]
          Cf[(long long)row * 768 + col] = v;
          Cbf[(long long)row * 768 + col] = f2bf(v);
        } else if constexpr (MODE == 2) {
          Cbf[(long long)b * cStr + (long long)row * ldc + col] = f2bf(v);
        } else if constexpr (MODE == 5) {
          v += aux[b * 768 + row] * aux2[col];         // + s1[b][d2]*u[d0]
          Cbf[(long long)b * cStr + (long long)row * ldc + col] = f2bf(v);
        } else {
          Cf[(long long)b * cStr + (long long)row * ldc + col] = v * SCALE + aux[b * 768 + col];
        }
      }
}

extern "C" void kernel_launch(void* const* d_in, const int* in_sizes, int n_in,
                              void* d_out, int out_size, void* d_ws, size_t ws_size,
                              hipStream_t stream)
{
  const float* query = (const float*)d_in[0];
  const float* key   = (const float*)d_in[1];
  const float* prev  = (const float*)d_in[3];
  const int*   mask  = (const int*)d_in[4];
  const float* Wq    = (const float*)d_in[5];
  const float* bq    = (const float*)d_in[6];
  const float* Wk    = (const float*)d_in[7];
  const float* bk    = (const float*)d_in[8];
  const float* Wc    = (const float*)d_in[11];
  const float* bc    = (const float*)d_in[12];
  float* out = (float*)d_out;

  char* p = (char*)d_ws;
  size_t off = 0;
  auto alloc = [&](size_t bytes) {
    char* r = p + off;
    off += (bytes + 255) & ~(size_t)255;
    return r;
  };
  unsigned short* keyzT_bf = (unsigned short*)alloc(4718592ull * 2);
  unsigned short* WqT_bf   = (unsigned short*)alloc(589824ull * 2);
  unsigned short* WkT_bf   = (unsigned short*)alloc(589824ull * 2);
  unsigned short* prev_bf  = (unsigned short*)alloc(589824ull * 2);
  unsigned short* Wc2_bf   = (unsigned short*)alloc(589824ull * 2);
  float*          Mt_f     = (float*)alloc(589824ull * 4);
  unsigned short* Mt_bf    = (unsigned short*)alloc(589824ull * 2);
  unsigned short* W2_bf    = (unsigned short*)alloc(589824ull * 2);
  unsigned short* Tt_bf    = (unsigned short*)alloc(4718592ull * 2);
  unsigned short* Pt_bf    = (unsigned short*)alloc(4718592ull * 2);
  float*          s1f      = (float*)alloc(6144ull * 4);
  float*          sm0f     = (float*)alloc(6144ull * 4);
  float*          uv       = (float*)alloc(768ull * 4);
  float*          w3v      = (float*)alloc(768ull * 4);
  float*          rowv     = (float*)alloc(6144ull * 4);
  (void)ws_size; (void)in_sizes; (void)n_in; (void)out_size;

  // prep
  k_tposeW<<<dim3(12, 12, 2), dim3(256), 0, stream>>>(Wq, Wk, WqT_bf, WkT_bf);
  k_prep<<<dim3(1152), dim3(256), 0, stream>>>(prev, Wc, prev_bf, Wc2_bf);
  k_cvtz<<<dim3(12, 12, 8), dim3(256), 0, stream>>>(key, mask, keyzT_bf);

  // G1: Mt = NT(Wc2, prev) + Wc1
  gemm_nt<0, 64, 64, 0><<<dim3(12, 12, 1), dim3(256), 0, stream>>>(
      (const void*)Wc2_bf, 0ll, 768, prev_bf, 0ll, 768, Mt_f, Mt_bf, 0ll, 768,
      Wc, (const float*)nullptr);
  // W2 = NT(WqT, WkT)
  gemm_nt<2, 64, 64, 0><<<dim3(12, 12, 1), dim3(256), 0, stream>>>(
      (const void*)WqT_bf, 0ll, 768, WkT_bf, 0ll, 768, (float*)nullptr, W2_bf, 0ll, 768,
      (const float*)nullptr, (const float*)nullptr);
  // u, w3
  k_scalars<<<dim3(384), dim3(256), 0, stream>>>(WqT_bf, WkT_bf, bk, bq, uv, w3v);
  // s1 / sm0 from fp32 Mt
  k_scol<<<dim3(1536), dim3(256), 0, stream>>>(Mt_f, mask, s1f, sm0f);
  // G3': Tt[b] = NT(Mt, keyzT[b])
  gemm_nt<2, 64, 64, 0><<<dim3(12, 12, 8), dim3(256), 0, stream>>>(
      (const void*)Mt_bf, 0ll, 768, keyzT_bf, 589824ll, 768, (float*)nullptr, Tt_bf,
      589824ll, 768, (const float*)nullptr, (const float*)nullptr);
  // G4': Pt[b] = NT(Tt[b], W2) + s1[b][m]*u[n]
  gemm_nt<5, 64, 64, 0><<<dim3(12, 12, 8), dim3(256), 0, stream>>>(
      (const void*)Tt_bf, 589824ll, 768, W2_bf, 0ll, 768, (float*)nullptr, Pt_bf,
      589824ll, 768, s1f, uv);
  // row constants
  k_row<<<dim3(1536), dim3(256), 0, stream>>>(Tt_bf, w3v, s1f, sm0f, bq, bk, bc, rowv);
  // G5: out = SCALE*NT(query_f32 reg-staged, Pt) + row
  gemm_nt<4, 128, 128, 1><<<dim3(6, 16, 8), dim3(256), 0, stream>>>(
      (const void*)query, 1572864ll, 768, Pt_bf, 589824ll, 768, out,
      (unsigned short*)nullptr, 1572864ll, 768, rowv, (const float*)nullptr);
}

// Round 9
// 124.722 us; speedup vs baseline: 1.1616x; 1.1616x over previous
//
#include <hip/hip_runtime.h>
#include <hip/hip_bf16.h>

// out[b] = SCALE*query[b]@P[b] + row[b]
//   M  = Wc1^T + prev@Wc2^T            (Mt = M^T, fp32+bf16)
//   Tt[b] = NT(Mt, keyzT[b])           (T = keyz^T@M; keyz = key rows zeroed by mask)
//   W2 = Wq^T@Wk,  u = Wq^T bk,  w3 = Wk^T bq
//   Pt[b] = NT(Tt[b], W2) + s1[b][d2]*u[d0]     (rank-1 bk-term folded in epilogue)
//   s1[b][d]  = sum_{mask=1} M[k][d],  sm0 = sum_{mask=0} M[k][d]
//   row[b][d] = bc[d] - 1e9*sm0[b][d] + SCALE*(w3@T[b] + (bq.bk)*s1[b][d])
//   G5: out = SCALE*NT(query_f32, Pt) + row.  query staged fp32 via gload_lds
//       as 2x128B HALF-ROWS with LOGICAL-row rotation slot=(g&7+r)&7 (2-way =
//       free; r7's 16-granule rotation was 4-way -> 2.36M conflicts), packed
//       to bf16 in-register at fragment read (v_perm).
// NT GEMMs: bf16 MFMA 16x16x32, BK=64, global_load_lds(16B), rotation LDS
// swizzle (bf16 path measured 0 conflicts), bijective XCD swizzle,
// single-buffer 2-barrier schedule (dbuf r6 and reg-staging r8 both regressed).

typedef __attribute__((ext_vector_type(8))) short short8;
typedef __attribute__((ext_vector_type(4))) float f32x4;
typedef __attribute__((ext_vector_type(4))) unsigned int u32x4;

#define SCALE 0.03608439182435161f   /* 1/sqrt(768) */

__device__ inline unsigned short f2bf(float x) {
  unsigned int u = __builtin_bit_cast(unsigned int, x);
  u = (u + 0x7fffu + ((u >> 16) & 1u)) >> 16;   // RNE
  return (unsigned short)u;
}
__device__ inline float bf2f(unsigned short h) {
  return __builtin_bit_cast(float, ((unsigned int)h) << 16);
}
__device__ inline unsigned int pack_trunc(float hi, float lo) {
  // {bf16(lo) | bf16(hi)<<16} via one v_perm (truncation; data path only)
  return __builtin_amdgcn_perm(__builtin_bit_cast(unsigned int, hi),
                               __builtin_bit_cast(unsigned int, lo), 0x07060302u);
}

// ---------------- prep kernels ----------------
// region 0: prev cvt, region 1: Wc2 slice cvt
__global__ void k_prep(const float* __restrict__ prev, const float* __restrict__ Wc,
                       unsigned short* __restrict__ prev_bf,
                       unsigned short* __restrict__ Wc2_bf) {
  int g = blockIdx.x;
  int region = g / 576;
  int idx = (g - region * 576) * 256 + threadIdx.x;       // < 147456 float4-groups
  float4 v;
  unsigned short* dst;
  if (region == 0) { v = reinterpret_cast<const float4*>(prev)[idx]; dst = prev_bf; }
  else {
    int r = idx / 192, c4 = (idx - r * 192) * 4;
    v = *reinterpret_cast<const float4*>(Wc + (long long)r * 1536 + 768 + c4);
    dst = Wc2_bf;
  }
  reinterpret_cast<ushort4*>(dst)[idx] = make_ushort4(f2bf(v.x), f2bf(v.y), f2bf(v.z), f2bf(v.w));
}

// z=0: WqT = Wq^T;  z=1: WkT = Wk^T  (LDS-tiled, bf16 out)
__global__ void k_tposeW(const float* __restrict__ Wq, const float* __restrict__ Wk,
                         unsigned short* __restrict__ WqT, unsigned short* __restrict__ WkT) {
  __shared__ float t[64][65];
  const float* src = blockIdx.z ? Wk : Wq;
  unsigned short* dst = blockIdx.z ? WkT : WqT;
  int bx = blockIdx.x * 64, by = blockIdx.y * 64;
  int tx = threadIdx.x & 63, ty = threadIdx.x >> 6;
  #pragma unroll
  for (int i = 0; i < 64; i += 4)
    t[ty + i][tx] = src[(long long)(by + ty + i) * 768 + bx + tx];
  __syncthreads();
  #pragma unroll
  for (int i = 0; i < 64; i += 4)
    dst[(long long)(bx + ty + i) * 768 + by + tx] = f2bf(t[tx][ty + i]);
}

// keyzT[b][d1][k] = f2bf(mask[b][k] ? key[b][k][d1] : 0)
__global__ void k_cvtz(const float* __restrict__ key, const int* __restrict__ mask,
                       unsigned short* __restrict__ keyzT) {
  __shared__ float t[64][65];
  int b = blockIdx.z;
  const float* src = key + (long long)b * 589824;
  unsigned short* dst = keyzT + (long long)b * 589824;
  const int* mb = mask + b * 768;
  int bx = blockIdx.x * 64, by = blockIdx.y * 64;   // by+r = k, bx+c = d1
  int tx = threadIdx.x & 63, ty = threadIdx.x >> 6;
  #pragma unroll
  for (int i = 0; i < 64; i += 4) {
    float v = src[(long long)(by + ty + i) * 768 + bx + tx];
    t[ty + i][tx] = mb[by + ty + i] ? v : 0.0f;
  }
  __syncthreads();
  #pragma unroll
  for (int i = 0; i < 64; i += 4)
    dst[(long long)(bx + ty + i) * 768 + by + tx] = f2bf(t[tx][ty + i]);
}

// u[d0] = sum_j WqT[d0][j]*bk[j];  w3[d1] = sum_j WkT[d1][j]*bq[j]
__global__ void k_scalars(const unsigned short* __restrict__ WqT,
                          const unsigned short* __restrict__ WkT,
                          const float* __restrict__ bk, const float* __restrict__ bq,
                          float* __restrict__ u, float* __restrict__ w3) {
  int gw = blockIdx.x * 4 + (threadIdx.x >> 6);
  int lane = threadIdx.x & 63;
  if (gw >= 1536) return;
  const unsigned short* wrow = (gw < 768) ? (WqT + (long long)gw * 768)
                                          : (WkT + (long long)(gw - 768) * 768);
  const float* vec = (gw < 768) ? bk : bq;
  float s = 0.f;
  for (int j = lane; j < 768; j += 64) s += bf2f(wrow[j]) * vec[j];
  #pragma unroll
  for (int off = 32; off > 0; off >>= 1) s += __shfl_down(s, off, 64);
  if (lane == 0) { if (gw < 768) u[gw] = s; else w3[gw - 768] = s; }
}

// s1[b][d2]=sum_{mask=1}Mt[d2][k]; sm0[b][d2]=sum_{mask=0}Mt[d2][k]  (fp32)
__global__ void k_scol(const float* __restrict__ Mt, const int* __restrict__ mask,
                       float* __restrict__ s1, float* __restrict__ sm0) {
  int gw = blockIdx.x * 4 + (threadIdx.x >> 6);
  int lane = threadIdx.x & 63;
  int b = gw / 768, d2 = gw - b * 768;
  if (b >= 8) return;
  const int* mb = mask + b * 768;
  const float* mrow = Mt + (long long)d2 * 768;
  float a1 = 0.f, a0 = 0.f;
  for (int k = lane; k < 768; k += 64) {
    float v = mrow[k];
    if (mb[k]) a1 += v; else a0 += v;
  }
  #pragma unroll
  for (int off = 32; off > 0; off >>= 1) {
    a1 += __shfl_down(a1, off, 64);
    a0 += __shfl_down(a0, off, 64);
  }
  if (lane == 0) { s1[gw] = a1; sm0[gw] = a0; }
}

// row[b][d2] = bc - 1e9*sm0 + SCALE*(sum_d1 Tt[b][d2][d1]*w3[d1] + (bq.bk)*s1)
__global__ void k_row(const unsigned short* __restrict__ Tt, const float* __restrict__ w3,
                      const float* __restrict__ s1, const float* __restrict__ sm0,
                      const float* __restrict__ bq, const float* __restrict__ bk,
                      const float* __restrict__ bc, float* __restrict__ row) {
  int gw = blockIdx.x * 4 + (threadIdx.x >> 6);
  int lane = threadIdx.x & 63;
  int b = gw / 768, d2 = gw - b * 768;
  if (b >= 8) return;
  const unsigned short* trow = Tt + ((long long)b * 768 + d2) * 768;
  float st = 0.f, sbb = 0.f;
  for (int j = lane; j < 768; j += 64) {
    st += bf2f(trow[j]) * w3[j];
    sbb += bq[j] * bk[j];
  }
  #pragma unroll
  for (int off = 32; off > 0; off >>= 1) {
    st += __shfl_down(st, off, 64);
    sbb += __shfl_down(sbb, off, 64);
  }
  if (lane == 0)
    row[gw] = bc[d2] - 1e9f * sm0[gw] + SCALE * (st + sbb * s1[gw]);
}

// ---------------- NT GEMM: C[m][n] = sum_k A[m][k]*B[n][k], K=768, BK=64 ----------
// MODE 0: Mt fp32+bf16 = acc + Wc1[m][n] (aux=Wc ld1536)
// MODE 2: bf16 = acc
// MODE 4: out fp32 = SCALE*acc + aux[b*768+n]              (row add)
// MODE 5: bf16 = acc + aux[b*768+m]*aux2[n]                (rank-1 fold)
// AF32=1: A fp32, stored as 2x128B half-rows (pr=2r+h), rotation by LOGICAL
//   row: slot=(g&7+r)&7 -> 2-way bank access (free). Packed to bf16 at read.
template <int MODE, int BM, int BN, int AF32>
__global__ __launch_bounds__(256) void gemm_nt(
    const void* __restrict__ A, long long aStr, int lda,
    const unsigned short* __restrict__ B, long long bStr, int ldb,
    float* __restrict__ Cf, unsigned short* __restrict__ Cbf,
    long long cStr, int ldc,
    const float* __restrict__ aux, const float* __restrict__ aux2)
{
  constexpr int BK = 64;
  constexpr int MI = BM / 32, NJ = BN / 32;
  constexpr int AGT = AF32 ? (BM * 16 / 256) : (BM * 8 / 256);
  constexpr int BGT = BN * 8 / 256;
  __shared__ __align__(16) char As[BM * BK * (AF32 ? 4 : 2)];
  __shared__ __align__(16) char Bs[BN * BK * 2];

  // bijective XCD swizzle (m204)
  const int gx = gridDim.x, gy = gridDim.y;
  const int nwg = gx * gy * (int)gridDim.z;
  int lin = blockIdx.x + gx * (blockIdx.y + gy * blockIdx.z);
  int qq = nwg >> 3, rr = nwg & 7, xcd = lin & 7, loc = lin >> 3;
  int swz = (xcd < rr ? xcd * (qq + 1) : rr * (qq + 1) + (xcd - rr) * qq) + loc;
  int bz = swz / (gx * gy);
  int rem = swz - bz * gx * gy;
  int by = rem / gx, bx = rem - by * gx;

  const int b = bz;
  const int m0 = by * BM, n0 = bx * BN;
  const unsigned short* Ab16 = (const unsigned short*)A + (long long)b * aStr;
  const float*          Abf  = (const float*)A + (long long)b * aStr;
  const unsigned short* Bb = B + (long long)b * bStr;

  const int tid = threadIdx.x;
  const int w = tid >> 6, lane = tid & 63;
  const int wr = w >> 1, wc = w & 1;       // 2x2 waves
  const int fr = lane & 15, fq = lane >> 4;

  f32x4 acc[MI][NJ] = {};

  for (int kt = 0; kt < 768; kt += BK) {
    __syncthreads();
    if constexpr (AF32) {
      // fp32 A: dest-linear; dest granule D -> pr=D>>3, slot=D&7, r=pr>>1, h=pr&1;
      // source granule (g&7) = (slot - r)&7 of half h.
      #pragma unroll
      for (int t = 0; t < AGT; ++t) {
        int D = t * 256 + tid;
        int pr = D >> 3, slot = D & 7;
        int r = pr >> 1, h = pr & 1;
        int sg = (slot - r) & 7;
        const float* ga = Abf + (long long)(m0 + r) * lda + kt + h * 32 + sg * 4;
        __builtin_amdgcn_global_load_lds(
            (const __attribute__((address_space(1))) void*)ga,
            (__attribute__((address_space(3))) void*)(As + D * 16), 16, 0, 0);
      }
    } else {
      #pragma unroll
      for (int t = 0; t < AGT; ++t) {
        int g = t * 256 + tid;
        int row = g >> 3, s = g & 7;
        int sg = (s - row) & 7;
        const unsigned short* ga = Ab16 + (long long)(m0 + row) * lda + kt + sg * 8;
        __builtin_amdgcn_global_load_lds(
            (const __attribute__((address_space(1))) void*)ga,
            (__attribute__((address_space(3))) void*)(As + g * 16), 16, 0, 0);
      }
    }
    #pragma unroll
    for (int t = 0; t < BGT; ++t) {
      int g = t * 256 + tid;
      int row = g >> 3, s = g & 7;
      int sg = (s - row) & 7;
      const unsigned short* gb = Bb + (long long)(n0 + row) * ldb + kt + sg * 8;
      __builtin_amdgcn_global_load_lds(
          (const __attribute__((address_space(1))) void*)gb,
          (__attribute__((address_space(3))) void*)(Bs + g * 16), 16, 0, 0);
    }
    __syncthreads();

    #pragma unroll
    for (int kk = 0; kk < 2; ++kk) {
      short8 af[MI], bfr[NJ];
      #pragma unroll
      for (int i = 0; i < MI; ++i) {
        int r = wr * (BM / 2) + i * 16 + fr;
        if constexpr (AF32) {
          int pr = 2 * r + kk;                        // half h = kk (gidx = kk*8+fq*2)
          int s0 = (fq * 2 + r) & 7;
          int s1g = (fq * 2 + 1 + r) & 7;
          f32x4 x = *reinterpret_cast<const f32x4*>(As + pr * 128 + s0 * 16);
          f32x4 y = *reinterpret_cast<const f32x4*>(As + pr * 128 + s1g * 16);
          u32x4 u4 = {pack_trunc(x[1], x[0]), pack_trunc(x[3], x[2]),
                      pack_trunc(y[1], y[0]), pack_trunc(y[3], y[2])};
          af[i] = __builtin_bit_cast(short8, u4);
        } else {
          int sgi = ((kk * 4 + fq) + r) & 7;          // rotation-swizzled granule
          af[i] = *reinterpret_cast<const short8*>(As + r * 128 + sgi * 16);
        }
      }
      #pragma unroll
      for (int j = 0; j < NJ; ++j) {
        int r = wc * (BN / 2) + j * 16 + fr;
        int sgj = ((kk * 4 + fq) + r) & 7;
        bfr[j] = *reinterpret_cast<const short8*>(Bs + r * 128 + sgj * 16);
      }
      #pragma unroll
      for (int i = 0; i < MI; ++i)
        #pragma unroll
        for (int j = 0; j < NJ; ++j)
          acc[i][j] = __builtin_amdgcn_mfma_f32_16x16x32_bf16(af[i], bfr[j], acc[i][j], 0, 0, 0);
    }
  }

  #pragma unroll
  for (int i = 0; i < MI; ++i)
    #pragma unroll
    for (int j = 0; j < NJ; ++j)
      #pragma unroll
      for (int r = 0; r < 4; ++r) {
        int row = m0 + wr * (BM / 2) + i * 16 + fq * 4 + r;  // C/D: col=lane&15, row=(lane>>4)*4+r
        int col = n0 + wc * (BN / 2) + j * 16 + fr;
        float v = acc[i][j][r];
        if constexpr (MODE == 0) {
          v += aux[(long long)row * 1536 + col];       // + Wc1[d2][k]
          Cf[(long long)row * 768 + col] = v;
          Cbf[(long long)row * 768 + col] = f2bf(v);
        } else if constexpr (MODE == 2) {
          Cbf[(long long)b * cStr + (long long)row * ldc + col] = f2bf(v);
        } else if constexpr (MODE == 5) {
          v += aux[b * 768 + row] * aux2[col];         // + s1[b][d2]*u[d0]
          Cbf[(long long)b * cStr + (long long)row * ldc + col] = f2bf(v);
        } else {
          Cf[(long long)b * cStr + (long long)row * ldc + col] = v * SCALE + aux[b * 768 + col];
        }
      }
}

extern "C" void kernel_launch(void* const* d_in, const int* in_sizes, int n_in,
                              void* d_out, int out_size, void* d_ws, size_t ws_size,
                              hipStream_t stream)
{
  const float* query = (const float*)d_in[0];
  const float* key   = (const float*)d_in[1];
  const float* prev  = (const float*)d_in[3];
  const int*   mask  = (const int*)d_in[4];
  const float* Wq    = (const float*)d_in[5];
  const float* bq    = (const float*)d_in[6];
  const float* Wk    = (const float*)d_in[7];
  const float* bk    = (const float*)d_in[8];
  const float* Wc    = (const float*)d_in[11];
  const float* bc    = (const float*)d_in[12];
  float* out = (float*)d_out;

  char* p = (char*)d_ws;
  size_t off = 0;
  auto alloc = [&](size_t bytes) {
    char* r = p + off;
    off += (bytes + 255) & ~(size_t)255;
    return r;
  };
  unsigned short* keyzT_bf = (unsigned short*)alloc(4718592ull * 2);
  unsigned short* WqT_bf   = (unsigned short*)alloc(589824ull * 2);
  unsigned short* WkT_bf   = (unsigned short*)alloc(589824ull * 2);
  unsigned short* prev_bf  = (unsigned short*)alloc(589824ull * 2);
  unsigned short* Wc2_bf   = (unsigned short*)alloc(589824ull * 2);
  float*          Mt_f     = (float*)alloc(589824ull * 4);
  unsigned short* Mt_bf    = (unsigned short*)alloc(589824ull * 2);
  unsigned short* W2_bf    = (unsigned short*)alloc(589824ull * 2);
  unsigned short* Tt_bf    = (unsigned short*)alloc(4718592ull * 2);
  unsigned short* Pt_bf    = (unsigned short*)alloc(4718592ull * 2);
  float*          s1f      = (float*)alloc(6144ull * 4);
  float*          sm0f     = (float*)alloc(6144ull * 4);
  float*          uv       = (float*)alloc(768ull * 4);
  float*          w3v      = (float*)alloc(768ull * 4);
  float*          rowv     = (float*)alloc(6144ull * 4);
  (void)ws_size; (void)in_sizes; (void)n_in; (void)out_size;

  // prep
  k_tposeW<<<dim3(12, 12, 2), dim3(256), 0, stream>>>(Wq, Wk, WqT_bf, WkT_bf);
  k_prep<<<dim3(1152), dim3(256), 0, stream>>>(prev, Wc, prev_bf, Wc2_bf);
  k_cvtz<<<dim3(12, 12, 8), dim3(256), 0, stream>>>(key, mask, keyzT_bf);

  // G1: Mt = NT(Wc2, prev) + Wc1
  gemm_nt<0, 64, 64, 0><<<dim3(12, 12, 1), dim3(256), 0, stream>>>(
      (const void*)Wc2_bf, 0ll, 768, prev_bf, 0ll, 768, Mt_f, Mt_bf, 0ll, 768,
      Wc, (const float*)nullptr);
  // W2 = NT(WqT, WkT)
  gemm_nt<2, 64, 64, 0><<<dim3(12, 12, 1), dim3(256), 0, stream>>>(
      (const void*)WqT_bf, 0ll, 768, WkT_bf, 0ll, 768, (float*)nullptr, W2_bf, 0ll, 768,
      (const float*)nullptr, (const float*)nullptr);
  // u, w3
  k_scalars<<<dim3(384), dim3(256), 0, stream>>>(WqT_bf, WkT_bf, bk, bq, uv, w3v);
  // s1 / sm0 from fp32 Mt
  k_scol<<<dim3(1536), dim3(256), 0, stream>>>(Mt_f, mask, s1f, sm0f);
  // G3': Tt[b] = NT(Mt, keyzT[b])
  gemm_nt<2, 64, 64, 0><<<dim3(12, 12, 8), dim3(256), 0, stream>>>(
      (const void*)Mt_bf, 0ll, 768, keyzT_bf, 589824ll, 768, (float*)nullptr, Tt_bf,
      589824ll, 768, (const float*)nullptr, (const float*)nullptr);
  // G4': Pt[b] = NT(Tt[b], W2) + s1[b][m]*u[n]
  gemm_nt<5, 64, 64, 0><<<dim3(12, 12, 8), dim3(256), 0, stream>>>(
      (const void*)Tt_bf, 589824ll, 768, W2_bf, 0ll, 768, (float*)nullptr, Pt_bf,
      589824ll, 768, s1f, uv);
  // row constants
  k_row<<<dim3(1536), dim3(256), 0, stream>>>(Tt_bf, w3v, s1f, sm0f, bq, bk, bc, rowv);
  // G5: out = SCALE*NT(query_f32 half-row-staged, Pt) + row
  gemm_nt<4, 128, 128, 1><<<dim3(6, 16, 8), dim3(256), 0, stream>>>(
      (const void*)query, 1572864ll, 768, Pt_bf, 589824ll, 768, out,
      (unsigned short*)nullptr, 1572864ll, 768, rowv, (const float*)nullptr);
}

// Round 10
// 121.408 us; speedup vs baseline: 1.1933x; 1.0273x over previous
//
#include <hip/hip_runtime.h>
#include <hip/hip_bf16.h>

// out[b] = SCALE*query[b]@P[b] + row[b]
//   M  = Wc1^T + prev@Wc2^T            (Mt = M^T, fp32+bf16)
//   Tt[b] = NT(Mt, keyzT[b])           (T = keyz^T@M; keyz = key rows zeroed by mask)
//   W2 = Wq^T@Wk,  u = Wq^T bk,  w3 = Wk^T bq
//   Pt[b] = NT(Tt[b], W2) + s1[b][d2]*u[d0]
//   s1[b][d]  = sum_{mask=1} M[k][d],  sm0 = sum_{mask=0} M[k][d]
//   row[b][d] = bc[d] - 1e9*sm0[b][d] + SCALE*(w3@T[b] + (bq.bk)*s1[b][d])
//   G5 (new): 8-phase-style pipelined GEMM, BM=256 BN=192 BK=64, 512 thr /
//     8 waves (2Mx4N), grid 4x8x8 = 256 blocks = exactly 1/CU. Raw s_barrier
//     phases (NOT __syncthreads -> no vmcnt drain), counted prefetch: next
//     K-tile's gloads issued phases 0-2, single asm vmcnt(0) at tile end.
//     setprio(1) around MFMA clusters. bf16 A (fp32-direct abandoned: 3 tries
//     all conflict-plagued ties).
// Other GEMMs: r5-proven 2-barrier 64x64 structure, rotation LDS swizzle
// (measured 0 conflicts), bijective XCD swizzle. Mask-constant path fp32.

typedef __attribute__((ext_vector_type(8))) short short8;
typedef __attribute__((ext_vector_type(4))) float f32x4;

#define SCALE 0.03608439182435161f   /* 1/sqrt(768) */

__device__ inline unsigned short f2bf(float x) {
  unsigned int u = __builtin_bit_cast(unsigned int, x);
  u = (u + 0x7fffu + ((u >> 16) & 1u)) >> 16;   // RNE
  return (unsigned short)u;
}
__device__ inline float bf2f(unsigned short h) {
  return __builtin_bit_cast(float, ((unsigned int)h) << 16);
}

// ---------------- prep kernels ----------------
__global__ void k_cvt(const float* __restrict__ s, unsigned short* __restrict__ d, int n4) {
  int i = blockIdx.x * 256 + threadIdx.x;
  if (i >= n4) return;
  float4 v = reinterpret_cast<const float4*>(s)[i];
  reinterpret_cast<ushort4*>(d)[i] = make_ushort4(f2bf(v.x), f2bf(v.y), f2bf(v.z), f2bf(v.w));
}

// region 0: prev cvt, region 1: Wc2 slice cvt
__global__ void k_prep(const float* __restrict__ prev, const float* __restrict__ Wc,
                       unsigned short* __restrict__ prev_bf,
                       unsigned short* __restrict__ Wc2_bf) {
  int g = blockIdx.x;
  int region = g / 576;
  int idx = (g - region * 576) * 256 + threadIdx.x;
  float4 v;
  unsigned short* dst;
  if (region == 0) { v = reinterpret_cast<const float4*>(prev)[idx]; dst = prev_bf; }
  else {
    int r = idx / 192, c4 = (idx - r * 192) * 4;
    v = *reinterpret_cast<const float4*>(Wc + (long long)r * 1536 + 768 + c4);
    dst = Wc2_bf;
  }
  reinterpret_cast<ushort4*>(dst)[idx] = make_ushort4(f2bf(v.x), f2bf(v.y), f2bf(v.z), f2bf(v.w));
}

// z=0: WqT = Wq^T;  z=1: WkT = Wk^T
__global__ void k_tposeW(const float* __restrict__ Wq, const float* __restrict__ Wk,
                         unsigned short* __restrict__ WqT, unsigned short* __restrict__ WkT) {
  __shared__ float t[64][65];
  const float* src = blockIdx.z ? Wk : Wq;
  unsigned short* dst = blockIdx.z ? WkT : WqT;
  int bx = blockIdx.x * 64, by = blockIdx.y * 64;
  int tx = threadIdx.x & 63, ty = threadIdx.x >> 6;
  #pragma unroll
  for (int i = 0; i < 64; i += 4)
    t[ty + i][tx] = src[(long long)(by + ty + i) * 768 + bx + tx];
  __syncthreads();
  #pragma unroll
  for (int i = 0; i < 64; i += 4)
    dst[(long long)(bx + ty + i) * 768 + by + tx] = f2bf(t[tx][ty + i]);
}

// keyzT[b][d1][k] = f2bf(mask[b][k] ? key[b][k][d1] : 0)
__global__ void k_cvtz(const float* __restrict__ key, const int* __restrict__ mask,
                       unsigned short* __restrict__ keyzT) {
  __shared__ float t[64][65];
  int b = blockIdx.z;
  const float* src = key + (long long)b * 589824;
  unsigned short* dst = keyzT + (long long)b * 589824;
  const int* mb = mask + b * 768;
  int bx = blockIdx.x * 64, by = blockIdx.y * 64;
  int tx = threadIdx.x & 63, ty = threadIdx.x >> 6;
  #pragma unroll
  for (int i = 0; i < 64; i += 4) {
    float v = src[(long long)(by + ty + i) * 768 + bx + tx];
    t[ty + i][tx] = mb[by + ty + i] ? v : 0.0f;
  }
  __syncthreads();
  #pragma unroll
  for (int i = 0; i < 64; i += 4)
    dst[(long long)(bx + ty + i) * 768 + by + tx] = f2bf(t[tx][ty + i]);
}

// u[d0] = WqT[d0]·bk;  w3[d1] = WkT[d1]·bq
__global__ void k_scalars(const unsigned short* __restrict__ WqT,
                          const unsigned short* __restrict__ WkT,
                          const float* __restrict__ bk, const float* __restrict__ bq,
                          float* __restrict__ u, float* __restrict__ w3) {
  int gw = blockIdx.x * 4 + (threadIdx.x >> 6);
  int lane = threadIdx.x & 63;
  if (gw >= 1536) return;
  const unsigned short* wrow = (gw < 768) ? (WqT + (long long)gw * 768)
                                          : (WkT + (long long)(gw - 768) * 768);
  const float* vec = (gw < 768) ? bk : bq;
  float s = 0.f;
  for (int j = lane; j < 768; j += 64) s += bf2f(wrow[j]) * vec[j];
  #pragma unroll
  for (int off = 32; off > 0; off >>= 1) s += __shfl_down(s, off, 64);
  if (lane == 0) { if (gw < 768) u[gw] = s; else w3[gw - 768] = s; }
}

// s1/sm0 column sums of Mt under mask (fp32)
__global__ void k_scol(const float* __restrict__ Mt, const int* __restrict__ mask,
                       float* __restrict__ s1, float* __restrict__ sm0) {
  int gw = blockIdx.x * 4 + (threadIdx.x >> 6);
  int lane = threadIdx.x & 63;
  int b = gw / 768, d2 = gw - b * 768;
  if (b >= 8) return;
  const int* mb = mask + b * 768;
  const float* mrow = Mt + (long long)d2 * 768;
  float a1 = 0.f, a0 = 0.f;
  for (int k = lane; k < 768; k += 64) {
    float v = mrow[k];
    if (mb[k]) a1 += v; else a0 += v;
  }
  #pragma unroll
  for (int off = 32; off > 0; off >>= 1) {
    a1 += __shfl_down(a1, off, 64);
    a0 += __shfl_down(a0, off, 64);
  }
  if (lane == 0) { s1[gw] = a1; sm0[gw] = a0; }
}

// row[b][d2] = bc - 1e9*sm0 + SCALE*(Tt[b][d2]·w3 + (bq·bk)*s1)
__global__ void k_row(const unsigned short* __restrict__ Tt, const float* __restrict__ w3,
                      const float* __restrict__ s1, const float* __restrict__ sm0,
                      const float* __restrict__ bq, const float* __restrict__ bk,
                      const float* __restrict__ bc, float* __restrict__ row) {
  int gw = blockIdx.x * 4 + (threadIdx.x >> 6);
  int lane = threadIdx.x & 63;
  int b = gw / 768, d2 = gw - b * 768;
  if (b >= 8) return;
  const unsigned short* trow = Tt + ((long long)b * 768 + d2) * 768;
  float st = 0.f, sbb = 0.f;
  for (int j = lane; j < 768; j += 64) {
    st += bf2f(trow[j]) * w3[j];
    sbb += bq[j] * bk[j];
  }
  #pragma unroll
  for (int off = 32; off > 0; off >>= 1) {
    st += __shfl_down(st, off, 64);
    sbb += __shfl_down(sbb, off, 64);
  }
  if (lane == 0)
    row[gw] = bc[d2] - 1e9f * sm0[gw] + SCALE * (st + sbb * s1[gw]);
}

// ---------------- small NT GEMM (r5-proven): 64x64, BK=64, 2-barrier ----------
// MODE 0: Mt fp32+bf16 = acc + Wc1[m][n];  MODE 2: bf16 = acc;
// MODE 5: bf16 = acc + aux[b*768+m]*aux2[n]
template <int MODE>
__global__ __launch_bounds__(256) void gemm_nt(
    const unsigned short* __restrict__ A, long long aStr, int lda,
    const unsigned short* __restrict__ B, long long bStr, int ldb,
    float* __restrict__ Cf, unsigned short* __restrict__ Cbf,
    long long cStr, int ldc,
    const float* __restrict__ aux, const float* __restrict__ aux2)
{
  constexpr int BM = 64, BN = 64, BK = 64;
  __shared__ __align__(16) char As[BM * BK * 2];
  __shared__ __align__(16) char Bs[BN * BK * 2];

  const int gx = gridDim.x, gy = gridDim.y;
  const int nwg = gx * gy * (int)gridDim.z;
  int lin = blockIdx.x + gx * (blockIdx.y + gy * blockIdx.z);
  int qq = nwg >> 3, rr = nwg & 7, xcd = lin & 7, loc = lin >> 3;
  int swz = (xcd < rr ? xcd * (qq + 1) : rr * (qq + 1) + (xcd - rr) * qq) + loc;
  int bz = swz / (gx * gy);
  int rem = swz - bz * gx * gy;
  int by = rem / gx, bx = rem - by * gx;

  const int b = bz;
  const unsigned short* Ab = A + (long long)b * aStr;
  const unsigned short* Bb = B + (long long)b * bStr;
  const int m0 = by * BM, n0 = bx * BN;

  const int tid = threadIdx.x;
  const int w = tid >> 6, lane = tid & 63;
  const int wr = w >> 1, wc = w & 1;
  const int fr = lane & 15, fq = lane >> 4;

  f32x4 acc[2][2] = {};

  for (int kt = 0; kt < 768; kt += BK) {
    __syncthreads();
    #pragma unroll
    for (int t = 0; t < 2; ++t) {
      int g = t * 256 + tid;
      int row = g >> 3, s = g & 7;
      int sg = (s - row) & 7;
      const unsigned short* ga = Ab + (long long)(m0 + row) * lda + kt + sg * 8;
      __builtin_amdgcn_global_load_lds(
          (const __attribute__((address_space(1))) void*)ga,
          (__attribute__((address_space(3))) void*)(As + g * 16), 16, 0, 0);
    }
    #pragma unroll
    for (int t = 0; t < 2; ++t) {
      int g = t * 256 + tid;
      int row = g >> 3, s = g & 7;
      int sg = (s - row) & 7;
      const unsigned short* gb = Bb + (long long)(n0 + row) * ldb + kt + sg * 8;
      __builtin_amdgcn_global_load_lds(
          (const __attribute__((address_space(1))) void*)gb,
          (__attribute__((address_space(3))) void*)(Bs + g * 16), 16, 0, 0);
    }
    __syncthreads();

    #pragma unroll
    for (int kk = 0; kk < 2; ++kk) {
      short8 af[2], bfr[2];
      #pragma unroll
      for (int i = 0; i < 2; ++i) {
        int r = wr * 32 + i * 16 + fr;
        int sgi = ((kk * 4 + fq) + r) & 7;
        af[i] = *reinterpret_cast<const short8*>(As + r * 128 + sgi * 16);
      }
      #pragma unroll
      for (int j = 0; j < 2; ++j) {
        int r = wc * 32 + j * 16 + fr;
        int sgj = ((kk * 4 + fq) + r) & 7;
        bfr[j] = *reinterpret_cast<const short8*>(Bs + r * 128 + sgj * 16);
      }
      #pragma unroll
      for (int i = 0; i < 2; ++i)
        #pragma unroll
        for (int j = 0; j < 2; ++j)
          acc[i][j] = __builtin_amdgcn_mfma_f32_16x16x32_bf16(af[i], bfr[j], acc[i][j], 0, 0, 0);
    }
  }

  #pragma unroll
  for (int i = 0; i < 2; ++i)
    #pragma unroll
    for (int j = 0; j < 2; ++j)
      #pragma unroll
      for (int r = 0; r < 4; ++r) {
        int row = m0 + wr * 32 + i * 16 + fq * 4 + r;
        int col = n0 + wc * 32 + j * 16 + fr;
        float v = acc[i][j][r];
        if constexpr (MODE == 0) {
          v += aux[(long long)row * 1536 + col];
          Cf[(long long)row * 768 + col] = v;
          Cbf[(long long)row * 768 + col] = f2bf(v);
        } else if constexpr (MODE == 2) {
          Cbf[(long long)b * cStr + (long long)row * ldc + col] = f2bf(v);
        } else {
          v += aux[b * 768 + row] * aux2[col];
          Cbf[(long long)b * cStr + (long long)row * ldc + col] = f2bf(v);
        }
      }
}

// ---------------- G5: pipelined 256x192 GEMM, 512 thr / 8 waves -----------------
// out[b][q][d2] = SCALE * sum_d0 query_bf[b][q][d0]*Pt[b][d2][d0] + rowv[b][d2]
__global__ __launch_bounds__(512, 1) void g5_pipe(
    const unsigned short* __restrict__ A,   // query_bf [8][2048][768]
    const unsigned short* __restrict__ B,   // Pt [8][768][768]
    float* __restrict__ C, const float* __restrict__ rowv)
{
  __shared__ __align__(16) char As[2][256 * 128];   // 2 x 32 KB
  __shared__ __align__(16) char Bs[2][192 * 128];   // 2 x 24 KB

  // XCD swizzle (grid 4*8*8 = 256, divisible by 8 -> simple chunking)
  int lin = blockIdx.x + 4 * (blockIdx.y + 8 * blockIdx.z);
  int swz = (lin & 7) * 32 + (lin >> 3);
  int bz = swz >> 5;
  int rem = swz & 31;
  int by = rem >> 2, bx = rem & 3;

  const int b = bz;
  const int m0 = by * 256, n0 = bx * 192;
  const unsigned short* Ab = A + (long long)b * 1572864;
  const unsigned short* Bb = B + (long long)b * 589824;

  const int tid = threadIdx.x;
  const int w = tid >> 6, lane = tid & 63;
  const int wr = w >> 2, wn = w & 3;       // 2 M-waves x 4 N-waves
  const int fr = lane & 15, fq = lane >> 4;

  f32x4 acc[8][3] = {};

  // staging: linear LDS dest granule g=row*8+slot; source granule (slot-row)&7
  auto stageA = [&](int buf, int kt, int s0, int ns) {
    for (int s = s0; s < s0 + ns; ++s) {
      int g = s * 512 + tid;
      int row = g >> 3, slot = g & 7;
      int sg = (slot - row) & 7;
      const unsigned short* ga = Ab + (long long)(m0 + row) * 768 + kt + sg * 8;
      __builtin_amdgcn_global_load_lds(
          (const __attribute__((address_space(1))) void*)ga,
          (__attribute__((address_space(3))) void*)(&As[buf][0] + g * 16), 16, 0, 0);
    }
  };
  auto stageB = [&](int buf, int kt, int s0, int ns) {
    for (int s = s0; s < s0 + ns; ++s) {
      int g = s * 512 + tid;
      int row = g >> 3, slot = g & 7;
      int sg = (slot - row) & 7;
      const unsigned short* gb = Bb + (long long)(n0 + row) * 768 + kt + sg * 8;
      __builtin_amdgcn_global_load_lds(
          (const __attribute__((address_space(1))) void*)gb,
          (__attribute__((address_space(3))) void*)(&Bs[buf][0] + g * 16), 16, 0, 0);
    }
  };

  // prologue: stage tile 0 into buf 0 (A: 4 instrs, B: 3)
  stageA(0, 0, 0, 4);
  stageB(0, 0, 0, 3);
  asm volatile("s_waitcnt vmcnt(0)" ::: "memory");
  __builtin_amdgcn_s_barrier();
  __builtin_amdgcn_sched_barrier(0);

  int cur = 0;
  for (int t = 0; t < 12; ++t) {
    const char* as = &As[cur][0];
    const char* bs = &Bs[cur][0];
    const int ktn = (t + 1) * 64;
    short8 a0[4], a1[4], bb[3];

    // ---- phase 0: reads (A0-3, B0-2 @ kk=0) ; stage next A granules 0-1
    #pragma unroll
    for (int i = 0; i < 4; ++i) {
      int r = wr * 128 + i * 16 + fr;
      a0[i] = *reinterpret_cast<const short8*>(as + r * 128 + (((fq) + r) & 7) * 16);
    }
    #pragma unroll
    for (int j = 0; j < 3; ++j) {
      int r = wn * 48 + j * 16 + fr;
      bb[j] = *reinterpret_cast<const short8*>(bs + r * 128 + (((fq) + r) & 7) * 16);
    }
    if (t < 11) stageA(cur ^ 1, ktn, 0, 2);
    __builtin_amdgcn_s_barrier();
    __builtin_amdgcn_s_setprio(1);
    #pragma unroll
    for (int i = 0; i < 4; ++i)
      #pragma unroll
      for (int j = 0; j < 3; ++j)
        acc[i][j] = __builtin_amdgcn_mfma_f32_16x16x32_bf16(a0[i], bb[j], acc[i][j], 0, 0, 0);
    __builtin_amdgcn_s_setprio(0);
    __builtin_amdgcn_s_barrier();

    // ---- phase 1: reads (A4-7 @ kk=0) ; stage next A 2-3 + B 0
    #pragma unroll
    for (int i = 0; i < 4; ++i) {
      int r = wr * 128 + (4 + i) * 16 + fr;
      a1[i] = *reinterpret_cast<const short8*>(as + r * 128 + (((fq) + r) & 7) * 16);
    }
    if (t < 11) { stageA(cur ^ 1, ktn, 2, 2); stageB(cur ^ 1, ktn, 0, 1); }
    __builtin_amdgcn_s_barrier();
    __builtin_amdgcn_s_setprio(1);
    #pragma unroll
    for (int i = 0; i < 4; ++i)
      #pragma unroll
      for (int j = 0; j < 3; ++j)
        acc[4 + i][j] = __builtin_amdgcn_mfma_f32_16x16x32_bf16(a1[i], bb[j], acc[4 + i][j], 0, 0, 0);
    __builtin_amdgcn_s_setprio(0);
    __builtin_amdgcn_s_barrier();

    // ---- phase 2: reads (A0-3, B0-2 @ kk=1) ; stage next B 1-2
    #pragma unroll
    for (int i = 0; i < 4; ++i) {
      int r = wr * 128 + i * 16 + fr;
      a0[i] = *reinterpret_cast<const short8*>(as + r * 128 + (((4 + fq) + r) & 7) * 16);
    }
    #pragma unroll
    for (int j = 0; j < 3; ++j) {
      int r = wn * 48 + j * 16 + fr;
      bb[j] = *reinterpret_cast<const short8*>(bs + r * 128 + (((4 + fq) + r) & 7) * 16);
    }
    if (t < 11) stageB(cur ^ 1, ktn, 1, 2);
    __builtin_amdgcn_s_barrier();
    __builtin_amdgcn_s_setprio(1);
    #pragma unroll
    for (int i = 0; i < 4; ++i)
      #pragma unroll
      for (int j = 0; j < 3; ++j)
        acc[i][j] = __builtin_amdgcn_mfma_f32_16x16x32_bf16(a0[i], bb[j], acc[i][j], 0, 0, 0);
    __builtin_amdgcn_s_setprio(0);
    __builtin_amdgcn_s_barrier();

    // ---- phase 3: reads (A4-7 @ kk=1)
    #pragma unroll
    for (int i = 0; i < 4; ++i) {
      int r = wr * 128 + (4 + i) * 16 + fr;
      a1[i] = *reinterpret_cast<const short8*>(as + r * 128 + (((4 + fq) + r) & 7) * 16);
    }
    __builtin_amdgcn_s_barrier();
    __builtin_amdgcn_s_setprio(1);
    #pragma unroll
    for (int i = 0; i < 4; ++i)
      #pragma unroll
      for (int j = 0; j < 3; ++j)
        acc[4 + i][j] = __builtin_amdgcn_mfma_f32_16x16x32_bf16(a1[i], bb[j], acc[4 + i][j], 0, 0, 0);
    __builtin_amdgcn_s_setprio(0);

    // ---- tile boundary: wait own prefetch loads, then converge
    if (t < 11) asm volatile("s_waitcnt vmcnt(0)" ::: "memory");
    __builtin_amdgcn_s_barrier();
    __builtin_amdgcn_sched_barrier(0);
    cur ^= 1;
  }

  // epilogue
  const long long ob = (long long)b * 1572864;
  #pragma unroll
  for (int i = 0; i < 8; ++i)
    #pragma unroll
    for (int j = 0; j < 3; ++j)
      #pragma unroll
      for (int r = 0; r < 4; ++r) {
        int row = m0 + wr * 128 + i * 16 + fq * 4 + r;
        int col = n0 + wn * 48 + j * 16 + fr;
        C[ob + (long long)row * 768 + col] = acc[i][j][r] * SCALE + rowv[b * 768 + col];
      }
}

extern "C" void kernel_launch(void* const* d_in, const int* in_sizes, int n_in,
                              void* d_out, int out_size, void* d_ws, size_t ws_size,
                              hipStream_t stream)
{
  const float* query = (const float*)d_in[0];
  const float* key   = (const float*)d_in[1];
  const float* prev  = (const float*)d_in[3];
  const int*   mask  = (const int*)d_in[4];
  const float* Wq    = (const float*)d_in[5];
  const float* bq    = (const float*)d_in[6];
  const float* Wk    = (const float*)d_in[7];
  const float* bk    = (const float*)d_in[8];
  const float* Wc    = (const float*)d_in[11];
  const float* bc    = (const float*)d_in[12];
  float* out = (float*)d_out;

  char* p = (char*)d_ws;
  size_t off = 0;
  auto alloc = [&](size_t bytes) {
    char* r = p + off;
    off += (bytes + 255) & ~(size_t)255;
    return r;
  };
  unsigned short* query_bf = (unsigned short*)alloc(12582912ull * 2);
  unsigned short* keyzT_bf = (unsigned short*)alloc(4718592ull * 2);
  unsigned short* WqT_bf   = (unsigned short*)alloc(589824ull * 2);
  unsigned short* WkT_bf   = (unsigned short*)alloc(589824ull * 2);
  unsigned short* prev_bf  = (unsigned short*)alloc(589824ull * 2);
  unsigned short* Wc2_bf   = (unsigned short*)alloc(589824ull * 2);
  float*          Mt_f     = (float*)alloc(589824ull * 4);
  unsigned short* Mt_bf    = (unsigned short*)alloc(589824ull * 2);
  unsigned short* W2_bf    = (unsigned short*)alloc(589824ull * 2);
  unsigned short* Tt_bf    = (unsigned short*)alloc(4718592ull * 2);
  unsigned short* Pt_bf    = (unsigned short*)alloc(4718592ull * 2);
  float*          s1f      = (float*)alloc(6144ull * 4);
  float*          sm0f     = (float*)alloc(6144ull * 4);
  float*          uv       = (float*)alloc(768ull * 4);
  float*          w3v      = (float*)alloc(768ull * 4);
  float*          rowv     = (float*)alloc(6144ull * 4);
  (void)ws_size; (void)in_sizes; (void)n_in; (void)out_size;

  // prep
  k_cvt<<<dim3(12288), dim3(256), 0, stream>>>(query, query_bf, 3145728);
  k_tposeW<<<dim3(12, 12, 2), dim3(256), 0, stream>>>(Wq, Wk, WqT_bf, WkT_bf);
  k_prep<<<dim3(1152), dim3(256), 0, stream>>>(prev, Wc, prev_bf, Wc2_bf);
  k_cvtz<<<dim3(12, 12, 8), dim3(256), 0, stream>>>(key, mask, keyzT_bf);

  // G1: Mt = NT(Wc2, prev) + Wc1
  gemm_nt<0><<<dim3(12, 12, 1), dim3(256), 0, stream>>>(
      Wc2_bf, 0ll, 768, prev_bf, 0ll, 768, Mt_f, Mt_bf, 0ll, 768,
      Wc, (const float*)nullptr);
  // W2 = NT(WqT, WkT)
  gemm_nt<2><<<dim3(12, 12, 1), dim3(256), 0, stream>>>(
      WqT_bf, 0ll, 768, WkT_bf, 0ll, 768, (float*)nullptr, W2_bf, 0ll, 768,
      (const float*)nullptr, (const float*)nullptr);
  // u, w3
  k_scalars<<<dim3(384), dim3(256), 0, stream>>>(WqT_bf, WkT_bf, bk, bq, uv, w3v);
  // s1 / sm0
  k_scol<<<dim3(1536), dim3(256), 0, stream>>>(Mt_f, mask, s1f, sm0f);
  // G3': Tt[b] = NT(Mt, keyzT[b])
  gemm_nt<2><<<dim3(12, 12, 8), dim3(256), 0, stream>>>(
      Mt_bf, 0ll, 768, keyzT_bf, 589824ll, 768, (float*)nullptr, Tt_bf,
      589824ll, 768, (const float*)nullptr, (const float*)nullptr);
  // G4': Pt[b] = NT(Tt[b], W2) + s1[b][m]*u[n]
  gemm_nt<5><<<dim3(12, 12, 8), dim3(256), 0, stream>>>(
      Tt_bf, 589824ll, 768, W2_bf, 0ll, 768, (float*)nullptr, Pt_bf,
      589824ll, 768, s1f, uv);
  // row constants
  k_row<<<dim3(1536), dim3(256), 0, stream>>>(Tt_bf, w3v, s1f, sm0f, bq, bk, bc, rowv);
  // G5: pipelined
  g5_pipe<<<dim3(4, 8, 8), dim3(512), 0, stream>>>(query_bf, Pt_bf, out, rowv);
}

// Round 11
// 116.138 us; speedup vs baseline: 1.2475x; 1.0454x over previous
//
#include <hip/hip_runtime.h>
#include <hip/hip_bf16.h>

// out[b] = SCALE*query[b]@P[b] + row[b]
//   M  = Wc1^T + prev@Wc2^T            (Mt = M^T, fp32+bf16)
//   Tt[b] = NT(Mt, keyzT[b])           (T = keyz^T@M; keyz = key rows zeroed by mask)
//   W2 = Wq^T@Wk,  u = Wq^T bk,  w3 = Wk^T bq
//   Pt[b] = NT(Tt[b], W2) + s1[b][d2]*u[d0]
//   s1[b][d]  = sum_{mask=1} M[k][d],  sm0 = sum_{mask=0} M[k][d]
//   row[b][d] = bc[d] - 1e9*sm0[b][d] + SCALE*(w3@T[b] + (bq.bk)*s1[b][d])
//   G5: r10 pipelined 256x192 BK=64, 512 thr / 8 waves, grid 256 = 1/CU,
//     raw-barrier phases + tile-end vmcnt(0) ("memory" clobber kept for
//     ordering), setprio around MFMA. CHANGE r11: removed the 12 in-loop
//     sched_barrier(0)s (m141: order-pinning kills compiler scheduling).
// Other GEMMs: r5-proven 2-barrier 64x64, rotation LDS swizzle (measured 0
// conflicts), bijective XCD swizzle. Mask-constant path fp32.
// Fusions r11: tposeW+cvtz -> k_tcvt; scalars+scol -> k_sums (-2 launches).

typedef __attribute__((ext_vector_type(8))) short short8;
typedef __attribute__((ext_vector_type(4))) float f32x4;

#define SCALE 0.03608439182435161f   /* 1/sqrt(768) */

__device__ inline unsigned short f2bf(float x) {
  unsigned int u = __builtin_bit_cast(unsigned int, x);
  u = (u + 0x7fffu + ((u >> 16) & 1u)) >> 16;   // RNE
  return (unsigned short)u;
}
__device__ inline float bf2f(unsigned short h) {
  return __builtin_bit_cast(float, ((unsigned int)h) << 16);
}

// ---------------- prep kernels ----------------
__global__ void k_cvt(const float* __restrict__ s, unsigned short* __restrict__ d, int n4) {
  int i = blockIdx.x * 256 + threadIdx.x;
  if (i >= n4) return;
  float4 v = reinterpret_cast<const float4*>(s)[i];
  reinterpret_cast<ushort4*>(d)[i] = make_ushort4(f2bf(v.x), f2bf(v.y), f2bf(v.z), f2bf(v.w));
}

// region 0: prev cvt, region 1: Wc2 slice cvt
__global__ void k_prep(const float* __restrict__ prev, const float* __restrict__ Wc,
                       unsigned short* __restrict__ prev_bf,
                       unsigned short* __restrict__ Wc2_bf) {
  int g = blockIdx.x;
  int region = g / 576;
  int idx = (g - region * 576) * 256 + threadIdx.x;
  float4 v;
  unsigned short* dst;
  if (region == 0) { v = reinterpret_cast<const float4*>(prev)[idx]; dst = prev_bf; }
  else {
    int r = idx / 192, c4 = (idx - r * 192) * 4;
    v = *reinterpret_cast<const float4*>(Wc + (long long)r * 1536 + 768 + c4);
    dst = Wc2_bf;
  }
  reinterpret_cast<ushort4*>(dst)[idx] = make_ushort4(f2bf(v.x), f2bf(v.y), f2bf(v.z), f2bf(v.w));
}

// fused transpose-cvt: z=0 WqT, z=1 WkT, z>=2 keyzT[b=z-2] (mask-zeroed rows)
__global__ void k_tcvt(const float* __restrict__ Wq, const float* __restrict__ Wk,
                       const float* __restrict__ key, const int* __restrict__ mask,
                       unsigned short* __restrict__ WqT, unsigned short* __restrict__ WkT,
                       unsigned short* __restrict__ keyzT) {
  __shared__ float t[64][65];
  int z = blockIdx.z;
  const float* src;
  unsigned short* dst;
  const int* mb = nullptr;
  if (z == 0) { src = Wq; dst = WqT; }
  else if (z == 1) { src = Wk; dst = WkT; }
  else {
    int b = z - 2;
    src = key + (long long)b * 589824;
    dst = keyzT + (long long)b * 589824;
    mb = mask + b * 768;
  }
  int bx = blockIdx.x * 64, by = blockIdx.y * 64;
  int tx = threadIdx.x & 63, ty = threadIdx.x >> 6;
  #pragma unroll
  for (int i = 0; i < 64; i += 4) {
    float v = src[(long long)(by + ty + i) * 768 + bx + tx];
    if (mb) v = mb[by + ty + i] ? v : 0.0f;
    t[ty + i][tx] = v;
  }
  __syncthreads();
  #pragma unroll
  for (int i = 0; i < 64; i += 4)
    dst[(long long)(bx + ty + i) * 768 + by + tx] = f2bf(t[tx][ty + i]);
}

// fused reductions: gw<1536 -> u/w3 scalars; gw>=1536 -> s1/sm0 column sums
__global__ void k_sums(const unsigned short* __restrict__ WqT,
                       const unsigned short* __restrict__ WkT,
                       const float* __restrict__ bk, const float* __restrict__ bq,
                       const float* __restrict__ Mt, const int* __restrict__ mask,
                       float* __restrict__ u, float* __restrict__ w3,
                       float* __restrict__ s1, float* __restrict__ sm0) {
  int gw = blockIdx.x * 4 + (threadIdx.x >> 6);
  int lane = threadIdx.x & 63;
  if (gw < 1536) {
    const unsigned short* wrow = (gw < 768) ? (WqT + (long long)gw * 768)
                                            : (WkT + (long long)(gw - 768) * 768);
    const float* vec = (gw < 768) ? bk : bq;
    float s = 0.f;
    for (int j = lane; j < 768; j += 64) s += bf2f(wrow[j]) * vec[j];
    #pragma unroll
    for (int off = 32; off > 0; off >>= 1) s += __shfl_down(s, off, 64);
    if (lane == 0) { if (gw < 768) u[gw] = s; else w3[gw - 768] = s; }
  } else {
    int g2 = gw - 1536;
    int b = g2 / 768, d2 = g2 - b * 768;
    if (b >= 8) return;
    const int* mb = mask + b * 768;
    const float* mrow = Mt + (long long)d2 * 768;
    float a1 = 0.f, a0 = 0.f;
    for (int k = lane; k < 768; k += 64) {
      float v = mrow[k];
      if (mb[k]) a1 += v; else a0 += v;
    }
    #pragma unroll
    for (int off = 32; off > 0; off >>= 1) {
      a1 += __shfl_down(a1, off, 64);
      a0 += __shfl_down(a0, off, 64);
    }
    if (lane == 0) { s1[g2] = a1; sm0[g2] = a0; }
  }
}

// row[b][d2] = bc - 1e9*sm0 + SCALE*(Tt[b][d2]·w3 + (bq·bk)*s1)
__global__ void k_row(const unsigned short* __restrict__ Tt, const float* __restrict__ w3,
                      const float* __restrict__ s1, const float* __restrict__ sm0,
                      const float* __restrict__ bq, const float* __restrict__ bk,
                      const float* __restrict__ bc, float* __restrict__ row) {
  int gw = blockIdx.x * 4 + (threadIdx.x >> 6);
  int lane = threadIdx.x & 63;
  int b = gw / 768, d2 = gw - b * 768;
  if (b >= 8) return;
  const unsigned short* trow = Tt + ((long long)b * 768 + d2) * 768;
  float st = 0.f, sbb = 0.f;
  for (int j = lane; j < 768; j += 64) {
    st += bf2f(trow[j]) * w3[j];
    sbb += bq[j] * bk[j];
  }
  #pragma unroll
  for (int off = 32; off > 0; off >>= 1) {
    st += __shfl_down(st, off, 64);
    sbb += __shfl_down(sbb, off, 64);
  }
  if (lane == 0)
    row[gw] = bc[d2] - 1e9f * sm0[gw] + SCALE * (st + sbb * s1[gw]);
}

// ---------------- small NT GEMM (r5-proven): 64x64, BK=64, 2-barrier ----------
// MODE 0: Mt fp32+bf16 = acc + Wc1[m][n];  MODE 2: bf16 = acc;
// MODE 5: bf16 = acc + aux[b*768+m]*aux2[n]
template <int MODE>
__global__ __launch_bounds__(256) void gemm_nt(
    const unsigned short* __restrict__ A, long long aStr, int lda,
    const unsigned short* __restrict__ B, long long bStr, int ldb,
    float* __restrict__ Cf, unsigned short* __restrict__ Cbf,
    long long cStr, int ldc,
    const float* __restrict__ aux, const float* __restrict__ aux2)
{
  constexpr int BM = 64, BN = 64, BK = 64;
  __shared__ __align__(16) char As[BM * BK * 2];
  __shared__ __align__(16) char Bs[BN * BK * 2];

  const int gx = gridDim.x, gy = gridDim.y;
  const int nwg = gx * gy * (int)gridDim.z;
  int lin = blockIdx.x + gx * (blockIdx.y + gy * blockIdx.z);
  int qq = nwg >> 3, rr = nwg & 7, xcd = lin & 7, loc = lin >> 3;
  int swz = (xcd < rr ? xcd * (qq + 1) : rr * (qq + 1) + (xcd - rr) * qq) + loc;
  int bz = swz / (gx * gy);
  int rem = swz - bz * gx * gy;
  int by = rem / gx, bx = rem - by * gx;

  const int b = bz;
  const unsigned short* Ab = A + (long long)b * aStr;
  const unsigned short* Bb = B + (long long)b * bStr;
  const int m0 = by * BM, n0 = bx * BN;

  const int tid = threadIdx.x;
  const int w = tid >> 6, lane = tid & 63;
  const int wr = w >> 1, wc = w & 1;
  const int fr = lane & 15, fq = lane >> 4;

  f32x4 acc[2][2] = {};

  for (int kt = 0; kt < 768; kt += BK) {
    __syncthreads();
    #pragma unroll
    for (int t = 0; t < 2; ++t) {
      int g = t * 256 + tid;
      int row = g >> 3, s = g & 7;
      int sg = (s - row) & 7;
      const unsigned short* ga = Ab + (long long)(m0 + row) * lda + kt + sg * 8;
      __builtin_amdgcn_global_load_lds(
          (const __attribute__((address_space(1))) void*)ga,
          (__attribute__((address_space(3))) void*)(As + g * 16), 16, 0, 0);
    }
    #pragma unroll
    for (int t = 0; t < 2; ++t) {
      int g = t * 256 + tid;
      int row = g >> 3, s = g & 7;
      int sg = (s - row) & 7;
      const unsigned short* gb = Bb + (long long)(n0 + row) * ldb + kt + sg * 8;
      __builtin_amdgcn_global_load_lds(
          (const __attribute__((address_space(1))) void*)gb,
          (__attribute__((address_space(3))) void*)(Bs + g * 16), 16, 0, 0);
    }
    __syncthreads();

    #pragma unroll
    for (int kk = 0; kk < 2; ++kk) {
      short8 af[2], bfr[2];
      #pragma unroll
      for (int i = 0; i < 2; ++i) {
        int r = wr * 32 + i * 16 + fr;
        int sgi = ((kk * 4 + fq) + r) & 7;
        af[i] = *reinterpret_cast<const short8*>(As + r * 128 + sgi * 16);
      }
      #pragma unroll
      for (int j = 0; j < 2; ++j) {
        int r = wc * 32 + j * 16 + fr;
        int sgj = ((kk * 4 + fq) + r) & 7;
        bfr[j] = *reinterpret_cast<const short8*>(Bs + r * 128 + sgj * 16);
      }
      #pragma unroll
      for (int i = 0; i < 2; ++i)
        #pragma unroll
        for (int j = 0; j < 2; ++j)
          acc[i][j] = __builtin_amdgcn_mfma_f32_16x16x32_bf16(af[i], bfr[j], acc[i][j], 0, 0, 0);
    }
  }

  #pragma unroll
  for (int i = 0; i < 2; ++i)
    #pragma unroll
    for (int j = 0; j < 2; ++j)
      #pragma unroll
      for (int r = 0; r < 4; ++r) {
        int row = m0 + wr * 32 + i * 16 + fq * 4 + r;
        int col = n0 + wc * 32 + j * 16 + fr;
        float v = acc[i][j][r];
        if constexpr (MODE == 0) {
          v += aux[(long long)row * 1536 + col];
          Cf[(long long)row * 768 + col] = v;
          Cbf[(long long)row * 768 + col] = f2bf(v);
        } else if constexpr (MODE == 2) {
          Cbf[(long long)b * cStr + (long long)row * ldc + col] = f2bf(v);
        } else {
          v += aux[b * 768 + row] * aux2[col];
          Cbf[(long long)b * cStr + (long long)row * ldc + col] = f2bf(v);
        }
      }
}

// ---------------- G5: pipelined 256x192 GEMM, 512 thr / 8 waves -----------------
// out[b][q][d2] = SCALE * sum_d0 query_bf[b][q][d0]*Pt[b][d2][d0] + rowv[b][d2]
__global__ __launch_bounds__(512, 1) void g5_pipe(
    const unsigned short* __restrict__ A,   // query_bf [8][2048][768]
    const unsigned short* __restrict__ B,   // Pt [8][768][768]
    float* __restrict__ C, const float* __restrict__ rowv)
{
  __shared__ __align__(16) char As[2][256 * 128];   // 2 x 32 KB
  __shared__ __align__(16) char Bs[2][192 * 128];   // 2 x 24 KB

  // XCD swizzle (grid 4*8*8 = 256, divisible by 8 -> simple chunking)
  int lin = blockIdx.x + 4 * (blockIdx.y + 8 * blockIdx.z);
  int swz = (lin & 7) * 32 + (lin >> 3);
  int bz = swz >> 5;
  int rem = swz & 31;
  int by = rem >> 2, bx = rem & 3;

  const int b = bz;
  const int m0 = by * 256, n0 = bx * 192;
  const unsigned short* Ab = A + (long long)b * 1572864;
  const unsigned short* Bb = B + (long long)b * 589824;

  const int tid = threadIdx.x;
  const int w = tid >> 6, lane = tid & 63;
  const int wr = w >> 2, wn = w & 3;       // 2 M-waves x 4 N-waves
  const int fr = lane & 15, fq = lane >> 4;

  f32x4 acc[8][3] = {};

  // staging: linear LDS dest granule g=row*8+slot; source granule (slot-row)&7
  auto stageA = [&](int buf, int kt, int s0, int ns) {
    for (int s = s0; s < s0 + ns; ++s) {
      int g = s * 512 + tid;
      int row = g >> 3, slot = g & 7;
      int sg = (slot - row) & 7;
      const unsigned short* ga = Ab + (long long)(m0 + row) * 768 + kt + sg * 8;
      __builtin_amdgcn_global_load_lds(
          (const __attribute__((address_space(1))) void*)ga,
          (__attribute__((address_space(3))) void*)(&As[buf][0] + g * 16), 16, 0, 0);
    }
  };
  auto stageB = [&](int buf, int kt, int s0, int ns) {
    for (int s = s0; s < s0 + ns; ++s) {
      int g = s * 512 + tid;
      int row = g >> 3, slot = g & 7;
      int sg = (slot - row) & 7;
      const unsigned short* gb = Bb + (long long)(n0 + row) * 768 + kt + sg * 8;
      __builtin_amdgcn_global_load_lds(
          (const __attribute__((address_space(1))) void*)gb,
          (__attribute__((address_space(3))) void*)(&Bs[buf][0] + g * 16), 16, 0, 0);
    }
  };

  // prologue: stage tile 0 into buf 0
  stageA(0, 0, 0, 4);
  stageB(0, 0, 0, 3);
  asm volatile("s_waitcnt vmcnt(0)" ::: "memory");
  __builtin_amdgcn_s_barrier();
  __builtin_amdgcn_sched_barrier(0);

  int cur = 0;
  for (int t = 0; t < 12; ++t) {
    const char* as = &As[cur][0];
    const char* bs = &Bs[cur][0];
    const int ktn = (t + 1) * 64;
    short8 a0[4], a1[4], bb[3];

    // ---- phase 0: reads (A0-3, B0-2 @ kk=0) ; stage next A granules 0-1
    #pragma unroll
    for (int i = 0; i < 4; ++i) {
      int r = wr * 128 + i * 16 + fr;
      a0[i] = *reinterpret_cast<const short8*>(as + r * 128 + (((fq) + r) & 7) * 16);
    }
    #pragma unroll
    for (int j = 0; j < 3; ++j) {
      int r = wn * 48 + j * 16 + fr;
      bb[j] = *reinterpret_cast<const short8*>(bs + r * 128 + (((fq) + r) & 7) * 16);
    }
    if (t < 11) stageA(cur ^ 1, ktn, 0, 2);
    __builtin_amdgcn_s_barrier();
    __builtin_amdgcn_s_setprio(1);
    #pragma unroll
    for (int i = 0; i < 4; ++i)
      #pragma unroll
      for (int j = 0; j < 3; ++j)
        acc[i][j] = __builtin_amdgcn_mfma_f32_16x16x32_bf16(a0[i], bb[j], acc[i][j], 0, 0, 0);
    __builtin_amdgcn_s_setprio(0);
    __builtin_amdgcn_s_barrier();

    // ---- phase 1: reads (A4-7 @ kk=0) ; stage next A 2-3 + B 0
    #pragma unroll
    for (int i = 0; i < 4; ++i) {
      int r = wr * 128 + (4 + i) * 16 + fr;
      a1[i] = *reinterpret_cast<const short8*>(as + r * 128 + (((fq) + r) & 7) * 16);
    }
    if (t < 11) { stageA(cur ^ 1, ktn, 2, 2); stageB(cur ^ 1, ktn, 0, 1); }
    __builtin_amdgcn_s_barrier();
    __builtin_amdgcn_s_setprio(1);
    #pragma unroll
    for (int i = 0; i < 4; ++i)
      #pragma unroll
      for (int j = 0; j < 3; ++j)
        acc[4 + i][j] = __builtin_amdgcn_mfma_f32_16x16x32_bf16(a1[i], bb[j], acc[4 + i][j], 0, 0, 0);
    __builtin_amdgcn_s_setprio(0);
    __builtin_amdgcn_s_barrier();

    // ---- phase 2: reads (A0-3, B0-2 @ kk=1) ; stage next B 1-2
    #pragma unroll
    for (int i = 0; i < 4; ++i) {
      int r = wr * 128 + i * 16 + fr;
      a0[i] = *reinterpret_cast<const short8*>(as + r * 128 + (((4 + fq) + r) & 7) * 16);
    }
    #pragma unroll
    for (int j = 0; j < 3; ++j) {
      int r = wn * 48 + j * 16 + fr;
      bb[j] = *reinterpret_cast<const short8*>(bs + r * 128 + (((4 + fq) + r) & 7) * 16);
    }
    if (t < 11) stageB(cur ^ 1, ktn, 1, 2);
    __builtin_amdgcn_s_barrier();
    __builtin_amdgcn_s_setprio(1);
    #pragma unroll
    for (int i = 0; i < 4; ++i)
      #pragma unroll
      for (int j = 0; j < 3; ++j)
        acc[i][j] = __builtin_amdgcn_mfma_f32_16x16x32_bf16(a0[i], bb[j], acc[i][j], 0, 0, 0);
    __builtin_amdgcn_s_setprio(0);
    __builtin_amdgcn_s_barrier();

    // ---- phase 3: reads (A4-7 @ kk=1)
    #pragma unroll
    for (int i = 0; i < 4; ++i) {
      int r = wr * 128 + (4 + i) * 16 + fr;
      a1[i] = *reinterpret_cast<const short8*>(as + r * 128 + (((4 + fq) + r) & 7) * 16);
    }
    __builtin_amdgcn_s_barrier();
    __builtin_amdgcn_s_setprio(1);
    #pragma unroll
    for (int i = 0; i < 4; ++i)
      #pragma unroll
      for (int j = 0; j < 3; ++j)
        acc[4 + i][j] = __builtin_amdgcn_mfma_f32_16x16x32_bf16(a1[i], bb[j], acc[4 + i][j], 0, 0, 0);
    __builtin_amdgcn_s_setprio(0);

    // ---- tile boundary: wait own prefetch loads, then converge
    // r11: sched_barrier(0) REMOVED here (m141: order-pinning regression).
    if (t < 11) asm volatile("s_waitcnt vmcnt(0)" ::: "memory");
    __builtin_amdgcn_s_barrier();
    cur ^= 1;
  }

  // epilogue
  const long long ob = (long long)b * 1572864;
  #pragma unroll
  for (int i = 0; i < 8; ++i)
    #pragma unroll
    for (int j = 0; j < 3; ++j)
      #pragma unroll
      for (int r = 0; r < 4; ++r) {
        int row = m0 + wr * 128 + i * 16 + fq * 4 + r;
        int col = n0 + wn * 48 + j * 16 + fr;
        C[ob + (long long)row * 768 + col] = acc[i][j][r] * SCALE + rowv[b * 768 + col];
      }
}

extern "C" void kernel_launch(void* const* d_in, const int* in_sizes, int n_in,
                              void* d_out, int out_size, void* d_ws, size_t ws_size,
                              hipStream_t stream)
{
  const float* query = (const float*)d_in[0];
  const float* key   = (const float*)d_in[1];
  const float* prev  = (const float*)d_in[3];
  const int*   mask  = (const int*)d_in[4];
  const float* Wq    = (const float*)d_in[5];
  const float* bq    = (const float*)d_in[6];
  const float* Wk    = (const float*)d_in[7];
  const float* bk    = (const float*)d_in[8];
  const float* Wc    = (const float*)d_in[11];
  const float* bc    = (const float*)d_in[12];
  float* out = (float*)d_out;

  char* p = (char*)d_ws;
  size_t off = 0;
  auto alloc = [&](size_t bytes) {
    char* r = p + off;
    off += (bytes + 255) & ~(size_t)255;
    return r;
  };
  unsigned short* query_bf = (unsigned short*)alloc(12582912ull * 2);
  unsigned short* keyzT_bf = (unsigned short*)alloc(4718592ull * 2);
  unsigned short* WqT_bf   = (unsigned short*)alloc(589824ull * 2);
  unsigned short* WkT_bf   = (unsigned short*)alloc(589824ull * 2);
  unsigned short* prev_bf  = (unsigned short*)alloc(589824ull * 2);
  unsigned short* Wc2_bf   = (unsigned short*)alloc(589824ull * 2);
  float*          Mt_f     = (float*)alloc(589824ull * 4);
  unsigned short* Mt_bf    = (unsigned short*)alloc(589824ull * 2);
  unsigned short* W2_bf    = (unsigned short*)alloc(589824ull * 2);
  unsigned short* Tt_bf    = (unsigned short*)alloc(4718592ull * 2);
  unsigned short* Pt_bf    = (unsigned short*)alloc(4718592ull * 2);
  float*          s1f      = (float*)alloc(6144ull * 4);
  float*          sm0f     = (float*)alloc(6144ull * 4);
  float*          uv       = (float*)alloc(768ull * 4);
  float*          w3v      = (float*)alloc(768ull * 4);
  float*          rowv     = (float*)alloc(6144ull * 4);
  (void)ws_size; (void)in_sizes; (void)n_in; (void)out_size;

  // prep
  k_cvt<<<dim3(12288), dim3(256), 0, stream>>>(query, query_bf, 3145728);
  k_tcvt<<<dim3(12, 12, 10), dim3(256), 0, stream>>>(Wq, Wk, key, mask,
                                                     WqT_bf, WkT_bf, keyzT_bf);
  k_prep<<<dim3(1152), dim3(256), 0, stream>>>(prev, Wc, prev_bf, Wc2_bf);

  // G1: Mt = NT(Wc2, prev) + Wc1
  gemm_nt<0><<<dim3(12, 12, 1), dim3(256), 0, stream>>>(
      Wc2_bf, 0ll, 768, prev_bf, 0ll, 768, Mt_f, Mt_bf, 0ll, 768,
      Wc, (const float*)nullptr);
  // W2 = NT(WqT, WkT)
  gemm_nt<2><<<dim3(12, 12, 1), dim3(256), 0, stream>>>(
      WqT_bf, 0ll, 768, WkT_bf, 0ll, 768, (float*)nullptr, W2_bf, 0ll, 768,
      (const float*)nullptr, (const float*)nullptr);
  // u, w3, s1, sm0 (fused reductions)
  k_sums<<<dim3(1920), dim3(256), 0, stream>>>(WqT_bf, WkT_bf, bk, bq, Mt_f, mask,
                                               uv, w3v, s1f, sm0f);
  // G3': Tt[b] = NT(Mt, keyzT[b])
  gemm_nt<2><<<dim3(12, 12, 8), dim3(256), 0, stream>>>(
      Mt_bf, 0ll, 768, keyzT_bf, 589824ll, 768, (float*)nullptr, Tt_bf,
      589824ll, 768, (const float*)nullptr, (const float*)nullptr);
  // G4': Pt[b] = NT(Tt[b], W2) + s1[b][m]*u[n]
  gemm_nt<5><<<dim3(12, 12, 8), dim3(256), 0, stream>>>(
      Tt_bf, 589824ll, 768, W2_bf, 0ll, 768, (float*)nullptr, Pt_bf,
      589824ll, 768, s1f, uv);
  // row constants
  k_row<<<dim3(1536), dim3(256), 0, stream>>>(Tt_bf, w3v, s1f, sm0f, bq, bk, bc, rowv);
  // G5: pipelined (sched_barrier-free loop)
  g5_pipe<<<dim3(4, 8, 8), dim3(512), 0, stream>>>(query_bf, Pt_bf, out, rowv);
}

// Round 12
// 115.423 us; speedup vs baseline: 1.2552x; 1.0062x over previous
//
#include <hip/hip_runtime.h>
#include <hip/hip_bf16.h>

// out[b] = SCALE*query[b]@P[b] + row[b]
//   M  = Wc1^T + prev@Wc2^T            (Mt = M^T, fp32+bf16)
//   Tt[b] = NT(Mt, keyzT[b]) ; W2 = Wq^T@Wk ; u = Wq^T bk ; w3 = Wk^T bq
//   Pt[b] = NT(Tt[b], W2) + s1[b][d2]*u[d0]
//   row[b][d] = bc - 1e9*sm0 + SCALE*(w3@T[b] + (bq.bk)*s1)
//   G5: pipelined 256x192 BK=64, 512 thr / 8 waves, grid 256 = 1/CU.
//     r12: COUNTED vmcnt (T4): 3 A-buffers (depth-2 prefetch on A from HBM),
//     2 B-buffers (Pt is L2-resident), boundary wait = vmcnt(4) not 0.
// Other GEMMs: r5-proven 2-barrier 64x64, rotation LDS swizzle (0 conflicts),
// bijective XCD swizzle. Mask-constant path fp32.

typedef __attribute__((ext_vector_type(8))) short short8;
typedef __attribute__((ext_vector_type(4))) float f32x4;

#define SCALE 0.03608439182435161f   /* 1/sqrt(768) */

__device__ inline unsigned short f2bf(float x) {
  unsigned int u = __builtin_bit_cast(unsigned int, x);
  u = (u + 0x7fffu + ((u >> 16) & 1u)) >> 16;   // RNE
  return (unsigned short)u;
}
__device__ inline float bf2f(unsigned short h) {
  return __builtin_bit_cast(float, ((unsigned int)h) << 16);
}

// ---------------- prep kernels ----------------
// 8 elems (32B) per thread; adjacent ushort4 stores merge to b128
__global__ void k_cvt8(const float* __restrict__ s, unsigned short* __restrict__ d, int n8) {
  int i = blockIdx.x * 256 + threadIdx.x;
  if (i >= n8) return;
  const float4* s4 = reinterpret_cast<const float4*>(s);
  float4 v0 = s4[2 * i], v1 = s4[2 * i + 1];
  ushort4* d4 = reinterpret_cast<ushort4*>(d);
  d4[2 * i]     = make_ushort4(f2bf(v0.x), f2bf(v0.y), f2bf(v0.z), f2bf(v0.w));
  d4[2 * i + 1] = make_ushort4(f2bf(v1.x), f2bf(v1.y), f2bf(v1.z), f2bf(v1.w));
}

// region 0: prev cvt, region 1: Wc2 slice cvt
__global__ void k_prep(const float* __restrict__ prev, const float* __restrict__ Wc,
                       unsigned short* __restrict__ prev_bf,
                       unsigned short* __restrict__ Wc2_bf) {
  int g = blockIdx.x;
  int region = g / 576;
  int idx = (g - region * 576) * 256 + threadIdx.x;
  float4 v;
  unsigned short* dst;
  if (region == 0) { v = reinterpret_cast<const float4*>(prev)[idx]; dst = prev_bf; }
  else {
    int r = idx / 192, c4 = (idx - r * 192) * 4;
    v = *reinterpret_cast<const float4*>(Wc + (long long)r * 1536 + 768 + c4);
    dst = Wc2_bf;
  }
  reinterpret_cast<ushort4*>(dst)[idx] = make_ushort4(f2bf(v.x), f2bf(v.y), f2bf(v.z), f2bf(v.w));
}

// fused transpose-cvt: z=0 WqT, z=1 WkT, z>=2 keyzT[b=z-2] (mask-zeroed rows)
__global__ void k_tcvt(const float* __restrict__ Wq, const float* __restrict__ Wk,
                       const float* __restrict__ key, const int* __restrict__ mask,
                       unsigned short* __restrict__ WqT, unsigned short* __restrict__ WkT,
                       unsigned short* __restrict__ keyzT) {
  __shared__ float t[64][65];
  int z = blockIdx.z;
  const float* src;
  unsigned short* dst;
  const int* mb = nullptr;
  if (z == 0) { src = Wq; dst = WqT; }
  else if (z == 1) { src = Wk; dst = WkT; }
  else {
    int b = z - 2;
    src = key + (long long)b * 589824;
    dst = keyzT + (long long)b * 589824;
    mb = mask + b * 768;
  }
  int bx = blockIdx.x * 64, by = blockIdx.y * 64;
  int tx = threadIdx.x & 63, ty = threadIdx.x >> 6;
  #pragma unroll
  for (int i = 0; i < 64; i += 4) {
    float v = src[(long long)(by + ty + i) * 768 + bx + tx];
    if (mb) v = mb[by + ty + i] ? v : 0.0f;
    t[ty + i][tx] = v;
  }
  __syncthreads();
  #pragma unroll
  for (int i = 0; i < 64; i += 4)
    dst[(long long)(bx + ty + i) * 768 + by + tx] = f2bf(t[tx][ty + i]);
}

// fused reductions: gw<1536 -> u/w3 scalars; gw>=1536 -> s1/sm0 column sums
__global__ void k_sums(const unsigned short* __restrict__ WqT,
                       const unsigned short* __restrict__ WkT,
                       const float* __restrict__ bk, const float* __restrict__ bq,
                       const float* __restrict__ Mt, const int* __restrict__ mask,
                       float* __restrict__ u, float* __restrict__ w3,
                       float* __restrict__ s1, float* __restrict__ sm0) {
  int gw = blockIdx.x * 4 + (threadIdx.x >> 6);
  int lane = threadIdx.x & 63;
  if (gw < 1536) {
    const unsigned short* wrow = (gw < 768) ? (WqT + (long long)gw * 768)
                                            : (WkT + (long long)(gw - 768) * 768);
    const float* vec = (gw < 768) ? bk : bq;
    float s = 0.f;
    for (int j = lane; j < 768; j += 64) s += bf2f(wrow[j]) * vec[j];
    #pragma unroll
    for (int off = 32; off > 0; off >>= 1) s += __shfl_down(s, off, 64);
    if (lane == 0) { if (gw < 768) u[gw] = s; else w3[gw - 768] = s; }
  } else {
    int g2 = gw - 1536;
    int b = g2 / 768, d2 = g2 - b * 768;
    if (b >= 8) return;
    const int* mb = mask + b * 768;
    const float* mrow = Mt + (long long)d2 * 768;
    float a1 = 0.f, a0 = 0.f;
    for (int k = lane; k < 768; k += 64) {
      float v = mrow[k];
      if (mb[k]) a1 += v; else a0 += v;
    }
    #pragma unroll
    for (int off = 32; off > 0; off >>= 1) {
      a1 += __shfl_down(a1, off, 64);
      a0 += __shfl_down(a0, off, 64);
    }
    if (lane == 0) { s1[g2] = a1; sm0[g2] = a0; }
  }
}

// row[b][d2] = bc - 1e9*sm0 + SCALE*(Tt[b][d2]·w3 + (bq·bk)*s1)
__global__ void k_row(const unsigned short* __restrict__ Tt, const float* __restrict__ w3,
                      const float* __restrict__ s1, const float* __restrict__ sm0,
                      const float* __restrict__ bq, const float* __restrict__ bk,
                      const float* __restrict__ bc, float* __restrict__ row) {
  int gw = blockIdx.x * 4 + (threadIdx.x >> 6);
  int lane = threadIdx.x & 63;
  int b = gw / 768, d2 = gw - b * 768;
  if (b >= 8) return;
  const unsigned short* trow = Tt + ((long long)b * 768 + d2) * 768;
  float st = 0.f, sbb = 0.f;
  for (int j = lane; j < 768; j += 64) {
    st += bf2f(trow[j]) * w3[j];
    sbb += bq[j] * bk[j];
  }
  #pragma unroll
  for (int off = 32; off > 0; off >>= 1) {
    st += __shfl_down(st, off, 64);
    sbb += __shfl_down(sbb, off, 64);
  }
  if (lane == 0)
    row[gw] = bc[d2] - 1e9f * sm0[gw] + SCALE * (st + sbb * s1[gw]);
}

// ---------------- small NT GEMM (r5-proven): 64x64, BK=64, 2-barrier ----------
template <int MODE>
__global__ __launch_bounds__(256) void gemm_nt(
    const unsigned short* __restrict__ A, long long aStr, int lda,
    const unsigned short* __restrict__ B, long long bStr, int ldb,
    float* __restrict__ Cf, unsigned short* __restrict__ Cbf,
    long long cStr, int ldc,
    const float* __restrict__ aux, const float* __restrict__ aux2)
{
  constexpr int BM = 64, BN = 64, BK = 64;
  __shared__ __align__(16) char As[BM * BK * 2];
  __shared__ __align__(16) char Bs[BN * BK * 2];

  const int gx = gridDim.x, gy = gridDim.y;
  const int nwg = gx * gy * (int)gridDim.z;
  int lin = blockIdx.x + gx * (blockIdx.y + gy * blockIdx.z);
  int qq = nwg >> 3, rr = nwg & 7, xcd = lin & 7, loc = lin >> 3;
  int swz = (xcd < rr ? xcd * (qq + 1) : rr * (qq + 1) + (xcd - rr) * qq) + loc;
  int bz = swz / (gx * gy);
  int rem = swz - bz * gx * gy;
  int by = rem / gx, bx = rem - by * gx;

  const int b = bz;
  const unsigned short* Ab = A + (long long)b * aStr;
  const unsigned short* Bb = B + (long long)b * bStr;
  const int m0 = by * BM, n0 = bx * BN;

  const int tid = threadIdx.x;
  const int w = tid >> 6, lane = tid & 63;
  const int wr = w >> 1, wc = w & 1;
  const int fr = lane & 15, fq = lane >> 4;

  f32x4 acc[2][2] = {};

  for (int kt = 0; kt < 768; kt += BK) {
    __syncthreads();
    #pragma unroll
    for (int t = 0; t < 2; ++t) {
      int g = t * 256 + tid;
      int row = g >> 3, s = g & 7;
      int sg = (s - row) & 7;
      const unsigned short* ga = Ab + (long long)(m0 + row) * lda + kt + sg * 8;
      __builtin_amdgcn_global_load_lds(
          (const __attribute__((address_space(1))) void*)ga,
          (__attribute__((address_space(3))) void*)(As + g * 16), 16, 0, 0);
    }
    #pragma unroll
    for (int t = 0; t < 2; ++t) {
      int g = t * 256 + tid;
      int row = g >> 3, s = g & 7;
      int sg = (s - row) & 7;
      const unsigned short* gb = Bb + (long long)(n0 + row) * ldb + kt + sg * 8;
      __builtin_amdgcn_global_load_lds(
          (const __attribute__((address_space(1))) void*)gb,
          (__attribute__((address_space(3))) void*)(Bs + g * 16), 16, 0, 0);
    }
    __syncthreads();

    #pragma unroll
    for (int kk = 0; kk < 2; ++kk) {
      short8 af[2], bfr[2];
      #pragma unroll
      for (int i = 0; i < 2; ++i) {
        int r = wr * 32 + i * 16 + fr;
        int sgi = ((kk * 4 + fq) + r) & 7;
        af[i] = *reinterpret_cast<const short8*>(As + r * 128 + sgi * 16);
      }
      #pragma unroll
      for (int j = 0; j < 2; ++j) {
        int r = wc * 32 + j * 16 + fr;
        int sgj = ((kk * 4 + fq) + r) & 7;
        bfr[j] = *reinterpret_cast<const short8*>(Bs + r * 128 + sgj * 16);
      }
      #pragma unroll
      for (int i = 0; i < 2; ++i)
        #pragma unroll
        for (int j = 0; j < 2; ++j)
          acc[i][j] = __builtin_amdgcn_mfma_f32_16x16x32_bf16(af[i], bfr[j], acc[i][j], 0, 0, 0);
    }
  }

  #pragma unroll
  for (int i = 0; i < 2; ++i)
    #pragma unroll
    for (int j = 0; j < 2; ++j)
      #pragma unroll
      for (int r = 0; r < 4; ++r) {
        int row = m0 + wr * 32 + i * 16 + fq * 4 + r;
        int col = n0 + wc * 32 + j * 16 + fr;
        float v = acc[i][j][r];
        if constexpr (MODE == 0) {
          v += aux[(long long)row * 1536 + col];
          Cf[(long long)row * 768 + col] = v;
          Cbf[(long long)row * 768 + col] = f2bf(v);
        } else if constexpr (MODE == 2) {
          Cbf[(long long)b * cStr + (long long)row * ldc + col] = f2bf(v);
        } else {
          v += aux[b * 768 + row] * aux2[col];
          Cbf[(long long)b * cStr + (long long)row * ldc + col] = f2bf(v);
        }
      }
}

// ---------------- G5: pipelined 256x192, counted vmcnt (T4), 3 A-bufs ----------
__global__ __launch_bounds__(512, 1) void g5_pipe(
    const unsigned short* __restrict__ A,   // query_bf [8][2048][768]
    const unsigned short* __restrict__ B,   // Pt [8][768][768]
    float* __restrict__ C, const float* __restrict__ rowv)
{
  __shared__ __align__(16) char As[3][256 * 128];   // 3 x 32 KB (depth-2 A prefetch)
  __shared__ __align__(16) char Bs[2][192 * 128];   // 2 x 24 KB (Pt L2-resident)

  int lin = blockIdx.x + 4 * (blockIdx.y + 8 * blockIdx.z);
  int swz = (lin & 7) * 32 + (lin >> 3);
  int bz = swz >> 5;
  int rem = swz & 31;
  int by = rem >> 2, bx = rem & 3;

  const int b = bz;
  const int m0 = by * 256, n0 = bx * 192;
  const unsigned short* Ab = A + (long long)b * 1572864;
  const unsigned short* Bb = B + (long long)b * 589824;

  const int tid = threadIdx.x;
  const int w = tid >> 6, lane = tid & 63;
  const int wr = w >> 2, wn = w & 3;       // 2 M-waves x 4 N-waves
  const int fr = lane & 15, fq = lane >> 4;

  f32x4 acc[8][3] = {};

  auto stageA = [&](int buf, int kt, int s0, int ns) {
    for (int s = s0; s < s0 + ns; ++s) {
      int g = s * 512 + tid;
      int row = g >> 3, slot = g & 7;
      int sg = (slot - row) & 7;
      const unsigned short* ga = Ab + (long long)(m0 + row) * 768 + kt + sg * 8;
      __builtin_amdgcn_global_load_lds(
          (const __attribute__((address_space(1))) void*)ga,
          (__attribute__((address_space(3))) void*)(&As[buf][0] + g * 16), 16, 0, 0);
    }
  };
  auto stageB = [&](int buf, int kt, int s0, int ns) {
    for (int s = s0; s < s0 + ns; ++s) {
      int g = s * 512 + tid;
      int row = g >> 3, slot = g & 7;
      int sg = (slot - row) & 7;
      const unsigned short* gb = Bb + (long long)(n0 + row) * 768 + kt + sg * 8;
      __builtin_amdgcn_global_load_lds(
          (const __attribute__((address_space(1))) void*)gb,
          (__attribute__((address_space(3))) void*)(&Bs[buf][0] + g * 16), 16, 0, 0);
    }
  };

  // prologue: A(0), B(0), then A(1) deep-prefetch; wait A0+B0 (A1 stays in flight)
  stageA(0, 0, 0, 4);
  stageB(0, 0, 0, 3);
  stageA(1, 64, 0, 4);
  asm volatile("s_waitcnt vmcnt(4)" ::: "memory");
  __builtin_amdgcn_s_barrier();

  for (int t = 0; t < 12; ++t) {
    const char* as = &As[t % 3][0];
    const char* bs = &Bs[t & 1][0];
    const int ktn1 = (t + 1) * 64, ktn2 = (t + 2) * 64;
    short8 a0[4], a1[4], bb[3];

    // ---- phase 0: reads (A0-3, B0-2 @ kk=0) ; stage B(t+1) granules 0-1
    #pragma unroll
    for (int i = 0; i < 4; ++i) {
      int r = wr * 128 + i * 16 + fr;
      a0[i] = *reinterpret_cast<const short8*>(as + r * 128 + (((fq) + r) & 7) * 16);
    }
    #pragma unroll
    for (int j = 0; j < 3; ++j) {
      int r = wn * 48 + j * 16 + fr;
      bb[j] = *reinterpret_cast<const short8*>(bs + r * 128 + (((fq) + r) & 7) * 16);
    }
    if (t < 11) stageB((t + 1) & 1, ktn1, 0, 2);
    __builtin_amdgcn_s_barrier();
    __builtin_amdgcn_s_setprio(1);
    #pragma unroll
    for (int i = 0; i < 4; ++i)
      #pragma unroll
      for (int j = 0; j < 3; ++j)
        acc[i][j] = __builtin_amdgcn_mfma_f32_16x16x32_bf16(a0[i], bb[j], acc[i][j], 0, 0, 0);
    __builtin_amdgcn_s_setprio(0);
    __builtin_amdgcn_s_barrier();

    // ---- phase 1: reads (A4-7 @ kk=0) ; stage B(t+1) granule 2, A(t+2) 0-1
    #pragma unroll
    for (int i = 0; i < 4; ++i) {
      int r = wr * 128 + (4 + i) * 16 + fr;
      a1[i] = *reinterpret_cast<const short8*>(as + r * 128 + (((fq) + r) & 7) * 16);
    }
    if (t < 11) stageB((t + 1) & 1, ktn1, 2, 1);
    if (t < 10) stageA((t + 2) % 3, ktn2, 0, 2);
    __builtin_amdgcn_s_barrier();
    __builtin_amdgcn_s_setprio(1);
    #pragma unroll
    for (int i = 0; i < 4; ++i)
      #pragma unroll
      for (int j = 0; j < 3; ++j)
        acc[4 + i][j] = __builtin_amdgcn_mfma_f32_16x16x32_bf16(a1[i], bb[j], acc[4 + i][j], 0, 0, 0);
    __builtin_amdgcn_s_setprio(0);
    __builtin_amdgcn_s_barrier();

    // ---- phase 2: reads (A0-3, B0-2 @ kk=1) ; stage A(t+2) granules 2-3
    #pragma unroll
    for (int i = 0; i < 4; ++i) {
      int r = wr * 128 + i * 16 + fr;
      a0[i] = *reinterpret_cast<const short8*>(as + r * 128 + (((4 + fq) + r) & 7) * 16);
    }
    #pragma unroll
    for (int j = 0; j < 3; ++j) {
      int r = wn * 48 + j * 16 + fr;
      bb[j] = *reinterpret_cast<const short8*>(bs + r * 128 + (((4 + fq) + r) & 7) * 16);
    }
    if (t < 10) stageA((t + 2) % 3, ktn2, 2, 2);
    __builtin_amdgcn_s_barrier();
    __builtin_amdgcn_s_setprio(1);
    #pragma unroll
    for (int i = 0; i < 4; ++i)
      #pragma unroll
      for (int j = 0; j < 3; ++j)
        acc[i][j] = __builtin_amdgcn_mfma_f32_16x16x32_bf16(a0[i], bb[j], acc[i][j], 0, 0, 0);
    __builtin_amdgcn_s_setprio(0);
    __builtin_amdgcn_s_barrier();

    // ---- phase 3: reads (A4-7 @ kk=1)
    #pragma unroll
    for (int i = 0; i < 4; ++i) {
      int r = wr * 128 + (4 + i) * 16 + fr;
      a1[i] = *reinterpret_cast<const short8*>(as + r * 128 + (((4 + fq) + r) & 7) * 16);
    }
    __builtin_amdgcn_s_barrier();
    __builtin_amdgcn_s_setprio(1);
    #pragma unroll
    for (int i = 0; i < 4; ++i)
      #pragma unroll
      for (int j = 0; j < 3; ++j)
        acc[4 + i][j] = __builtin_amdgcn_mfma_f32_16x16x32_bf16(a1[i], bb[j], acc[4 + i][j], 0, 0, 0);
    __builtin_amdgcn_s_setprio(0);

    // ---- boundary: counted wait (T4). Newest 4 in flight = A(t+2) -> vmcnt(4)
    // ensures A(t+1) [issued t-1] and B(t+1) [issued this tile] complete.
    if (t < 10)       asm volatile("s_waitcnt vmcnt(4)" ::: "memory");
    else if (t == 10) asm volatile("s_waitcnt vmcnt(0)" ::: "memory");
    __builtin_amdgcn_s_barrier();
  }

  // epilogue
  const long long ob = (long long)b * 1572864;
  #pragma unroll
  for (int i = 0; i < 8; ++i)
    #pragma unroll
    for (int j = 0; j < 3; ++j)
      #pragma unroll
      for (int r = 0; r < 4; ++r) {
        int row = m0 + wr * 128 + i * 16 + fq * 4 + r;
        int col = n0 + wn * 48 + j * 16 + fr;
        C[ob + (long long)row * 768 + col] = acc[i][j][r] * SCALE + rowv[b * 768 + col];
      }
}

extern "C" void kernel_launch(void* const* d_in, const int* in_sizes, int n_in,
                              void* d_out, int out_size, void* d_ws, size_t ws_size,
                              hipStream_t stream)
{
  const float* query = (const float*)d_in[0];
  const float* key   = (const float*)d_in[1];
  const float* prev  = (const float*)d_in[3];
  const int*   mask  = (const int*)d_in[4];
  const float* Wq    = (const float*)d_in[5];
  const float* bq    = (const float*)d_in[6];
  const float* Wk    = (const float*)d_in[7];
  const float* bk    = (const float*)d_in[8];
  const float* Wc    = (const float*)d_in[11];
  const float* bc    = (const float*)d_in[12];
  float* out = (float*)d_out;

  char* p = (char*)d_ws;
  size_t off = 0;
  auto alloc = [&](size_t bytes) {
    char* r = p + off;
    off += (bytes + 255) & ~(size_t)255;
    return r;
  };
  unsigned short* query_bf = (unsigned short*)alloc(12582912ull * 2);
  unsigned short* keyzT_bf = (unsigned short*)alloc(4718592ull * 2);
  unsigned short* WqT_bf   = (unsigned short*)alloc(589824ull * 2);
  unsigned short* WkT_bf   = (unsigned short*)alloc(589824ull * 2);
  unsigned short* prev_bf  = (unsigned short*)alloc(589824ull * 2);
  unsigned short* Wc2_bf   = (unsigned short*)alloc(589824ull * 2);
  float*          Mt_f     = (float*)alloc(589824ull * 4);
  unsigned short* Mt_bf    = (unsigned short*)alloc(589824ull * 2);
  unsigned short* W2_bf    = (unsigned short*)alloc(589824ull * 2);
  unsigned short* Tt_bf    = (unsigned short*)alloc(4718592ull * 2);
  unsigned short* Pt_bf    = (unsigned short*)alloc(4718592ull * 2);
  float*          s1f      = (float*)alloc(6144ull * 4);
  float*          sm0f     = (float*)alloc(6144ull * 4);
  float*          uv       = (float*)alloc(768ull * 4);
  float*          w3v      = (float*)alloc(768ull * 4);
  float*          rowv     = (float*)alloc(6144ull * 4);
  (void)ws_size; (void)in_sizes; (void)n_in; (void)out_size;

  // prep
  k_cvt8<<<dim3(6144), dim3(256), 0, stream>>>(query, query_bf, 1572864);
  k_tcvt<<<dim3(12, 12, 10), dim3(256), 0, stream>>>(Wq, Wk, key, mask,
                                                     WqT_bf, WkT_bf, keyzT_bf);
  k_prep<<<dim3(1152), dim3(256), 0, stream>>>(prev, Wc, prev_bf, Wc2_bf);

  // G1: Mt = NT(Wc2, prev) + Wc1
  gemm_nt<0><<<dim3(12, 12, 1), dim3(256), 0, stream>>>(
      Wc2_bf, 0ll, 768, prev_bf, 0ll, 768, Mt_f, Mt_bf, 0ll, 768,
      Wc, (const float*)nullptr);
  // W2 = NT(WqT, WkT)
  gemm_nt<2><<<dim3(12, 12, 1), dim3(256), 0, stream>>>(
      WqT_bf, 0ll, 768, WkT_bf, 0ll, 768, (float*)nullptr, W2_bf, 0ll, 768,
      (const float*)nullptr, (const float*)nullptr);
  // u, w3, s1, sm0 (fused reductions)
  k_sums<<<dim3(1920), dim3(256), 0, stream>>>(WqT_bf, WkT_bf, bk, bq, Mt_f, mask,
                                               uv, w3v, s1f, sm0f);
  // G3': Tt[b] = NT(Mt, keyzT[b])
  gemm_nt<2><<<dim3(12, 12, 8), dim3(256), 0, stream>>>(
      Mt_bf, 0ll, 768, keyzT_bf, 589824ll, 768, (float*)nullptr, Tt_bf,
      589824ll, 768, (const float*)nullptr, (const float*)nullptr);
  // G4': Pt[b] = NT(Tt[b], W2) + s1[b][m]*u[n]
  gemm_nt<5><<<dim3(12, 12, 8), dim3(256), 0, stream>>>(
      Tt_bf, 589824ll, 768, W2_bf, 0ll, 768, (float*)nullptr, Pt_bf,
      589824ll, 768, s1f, uv);
  // row constants
  k_row<<<dim3(1536), dim3(256), 0, stream>>>(Tt_bf, w3v, s1f, sm0f, bq, bk, bc, rowv);
  // G5: counted-vmcnt pipeline
  g5_pipe<<<dim3(4, 8, 8), dim3(512), 0, stream>>>(query_bf, Pt_bf, out, rowv);
}

// Round 13
// 110.398 us; speedup vs baseline: 1.3123x; 1.0455x over previous
//
#include <hip/hip_runtime.h>
#include <hip/hip_bf16.h>

// out[b] = SCALE*query[b]@P[b] + row[b]
//   M  = Wc1^T + prev@Wc2^T            (Mt = M^T, fp32+bf16)
//   Tt[b] = NT(Mt, keyzT[b]) ; W2 = Wq^T@Wk ; u = Wq^T bk ; w3 = Wk^T bq
//   Pt[b] = NT(Tt[b], W2) + s1[b][d2]*u[d0]
//   row[b][d] = bc - 1e9*sm0 + SCALE*(w3@T[b] + (bq.bk)*s1)
//   G5: pipelined 256x192 BK=64, 512 thr / 8 waves, grid 256 = 1/CU.
//     r13: ONE barrier per K-tile (was 8; r10-12 showed schedule variants all
//     ~flat -> barrier count is the residual). Counted vmcnt(4) kept (3 A-bufs
//     depth-2, 2 B-bufs depth-1), setprio around MFMA clusters.
// Other GEMMs: r5-proven 2-barrier 64x64, rotation LDS swizzle (0 conflicts),
// bijective XCD swizzle. Mask-constant path fp32. r13: G1+W2 fused (1 launch).

typedef __attribute__((ext_vector_type(8))) short short8;
typedef __attribute__((ext_vector_type(4))) float f32x4;

#define SCALE 0.03608439182435161f   /* 1/sqrt(768) */

__device__ inline unsigned short f2bf(float x) {
  unsigned int u = __builtin_bit_cast(unsigned int, x);
  u = (u + 0x7fffu + ((u >> 16) & 1u)) >> 16;   // RNE
  return (unsigned short)u;
}
__device__ inline float bf2f(unsigned short h) {
  return __builtin_bit_cast(float, ((unsigned int)h) << 16);
}

// ---------------- prep kernels ----------------
__global__ void k_cvt8(const float* __restrict__ s, unsigned short* __restrict__ d, int n8) {
  int i = blockIdx.x * 256 + threadIdx.x;
  if (i >= n8) return;
  const float4* s4 = reinterpret_cast<const float4*>(s);
  float4 v0 = s4[2 * i], v1 = s4[2 * i + 1];
  ushort4* d4 = reinterpret_cast<ushort4*>(d);
  d4[2 * i]     = make_ushort4(f2bf(v0.x), f2bf(v0.y), f2bf(v0.z), f2bf(v0.w));
  d4[2 * i + 1] = make_ushort4(f2bf(v1.x), f2bf(v1.y), f2bf(v1.z), f2bf(v1.w));
}

// region 0: prev cvt, region 1: Wc2 slice cvt
__global__ void k_prep(const float* __restrict__ prev, const float* __restrict__ Wc,
                       unsigned short* __restrict__ prev_bf,
                       unsigned short* __restrict__ Wc2_bf) {
  int g = blockIdx.x;
  int region = g / 576;
  int idx = (g - region * 576) * 256 + threadIdx.x;
  float4 v;
  unsigned short* dst;
  if (region == 0) { v = reinterpret_cast<const float4*>(prev)[idx]; dst = prev_bf; }
  else {
    int r = idx / 192, c4 = (idx - r * 192) * 4;
    v = *reinterpret_cast<const float4*>(Wc + (long long)r * 1536 + 768 + c4);
    dst = Wc2_bf;
  }
  reinterpret_cast<ushort4*>(dst)[idx] = make_ushort4(f2bf(v.x), f2bf(v.y), f2bf(v.z), f2bf(v.w));
}

// fused transpose-cvt: z=0 WqT, z=1 WkT, z>=2 keyzT[b=z-2] (mask-zeroed rows)
__global__ void k_tcvt(const float* __restrict__ Wq, const float* __restrict__ Wk,
                       const float* __restrict__ key, const int* __restrict__ mask,
                       unsigned short* __restrict__ WqT, unsigned short* __restrict__ WkT,
                       unsigned short* __restrict__ keyzT) {
  __shared__ float t[64][65];
  int z = blockIdx.z;
  const float* src;
  unsigned short* dst;
  const int* mb = nullptr;
  if (z == 0) { src = Wq; dst = WqT; }
  else if (z == 1) { src = Wk; dst = WkT; }
  else {
    int b = z - 2;
    src = key + (long long)b * 589824;
    dst = keyzT + (long long)b * 589824;
    mb = mask + b * 768;
  }
  int bx = blockIdx.x * 64, by = blockIdx.y * 64;
  int tx = threadIdx.x & 63, ty = threadIdx.x >> 6;
  #pragma unroll
  for (int i = 0; i < 64; i += 4) {
    float v = src[(long long)(by + ty + i) * 768 + bx + tx];
    if (mb) v = mb[by + ty + i] ? v : 0.0f;
    t[ty + i][tx] = v;
  }
  __syncthreads();
  #pragma unroll
  for (int i = 0; i < 64; i += 4)
    dst[(long long)(bx + ty + i) * 768 + by + tx] = f2bf(t[tx][ty + i]);
}

// fused reductions: gw<1536 -> u/w3 scalars; gw>=1536 -> s1/sm0 column sums
__global__ void k_sums(const unsigned short* __restrict__ WqT,
                       const unsigned short* __restrict__ WkT,
                       const float* __restrict__ bk, const float* __restrict__ bq,
                       const float* __restrict__ Mt, const int* __restrict__ mask,
                       float* __restrict__ u, float* __restrict__ w3,
                       float* __restrict__ s1, float* __restrict__ sm0) {
  int gw = blockIdx.x * 4 + (threadIdx.x >> 6);
  int lane = threadIdx.x & 63;
  if (gw < 1536) {
    const unsigned short* wrow = (gw < 768) ? (WqT + (long long)gw * 768)
                                            : (WkT + (long long)(gw - 768) * 768);
    const float* vec = (gw < 768) ? bk : bq;
    float s = 0.f;
    for (int j = lane; j < 768; j += 64) s += bf2f(wrow[j]) * vec[j];
    #pragma unroll
    for (int off = 32; off > 0; off >>= 1) s += __shfl_down(s, off, 64);
    if (lane == 0) { if (gw < 768) u[gw] = s; else w3[gw - 768] = s; }
  } else {
    int g2 = gw - 1536;
    int b = g2 / 768, d2 = g2 - b * 768;
    if (b >= 8) return;
    const int* mb = mask + b * 768;
    const float* mrow = Mt + (long long)d2 * 768;
    float a1 = 0.f, a0 = 0.f;
    for (int k = lane; k < 768; k += 64) {
      float v = mrow[k];
      if (mb[k]) a1 += v; else a0 += v;
    }
    #pragma unroll
    for (int off = 32; off > 0; off >>= 1) {
      a1 += __shfl_down(a1, off, 64);
      a0 += __shfl_down(a0, off, 64);
    }
    if (lane == 0) { s1[g2] = a1; sm0[g2] = a0; }
  }
}

// row[b][d2] = bc - 1e9*sm0 + SCALE*(Tt[b][d2]·w3 + (bq·bk)*s1)
__global__ void k_row(const unsigned short* __restrict__ Tt, const float* __restrict__ w3,
                      const float* __restrict__ s1, const float* __restrict__ sm0,
                      const float* __restrict__ bq, const float* __restrict__ bk,
                      const float* __restrict__ bc, float* __restrict__ row) {
  int gw = blockIdx.x * 4 + (threadIdx.x >> 6);
  int lane = threadIdx.x & 63;
  int b = gw / 768, d2 = gw - b * 768;
  if (b >= 8) return;
  const unsigned short* trow = Tt + ((long long)b * 768 + d2) * 768;
  float st = 0.f, sbb = 0.f;
  for (int j = lane; j < 768; j += 64) {
    st += bf2f(trow[j]) * w3[j];
    sbb += bq[j] * bk[j];
  }
  #pragma unroll
  for (int off = 32; off > 0; off >>= 1) {
    st += __shfl_down(st, off, 64);
    sbb += __shfl_down(sbb, off, 64);
  }
  if (lane == 0)
    row[gw] = bc[d2] - 1e9f * sm0[gw] + SCALE * (st + sbb * s1[gw]);
}

// ---------------- shared 64x64 GEMM body pieces ----------------
__device__ inline void xcd_swz(int& bx, int& by, int& bz) {
  const int gx = gridDim.x, gy = gridDim.y;
  const int nwg = gx * gy * (int)gridDim.z;
  int lin = blockIdx.x + gx * (blockIdx.y + gy * blockIdx.z);
  int qq = nwg >> 3, rr = nwg & 7, xcd = lin & 7, loc = lin >> 3;
  int swz = (xcd < rr ? xcd * (qq + 1) : rr * (qq + 1) + (xcd - rr) * qq) + loc;
  bz = swz / (gx * gy);
  int rem = swz - bz * gx * gy;
  by = rem / gx;
  bx = rem - by * gx;
}

// core 64x64 NT loop: returns acc
__device__ inline void nt64_core(const unsigned short* Ab, int lda,
                                 const unsigned short* Bb, int ldb,
                                 int m0, int n0, int tid, f32x4 (&acc)[2][2],
                                 char* As, char* Bs) {
  const int w = tid >> 6, lane = tid & 63;
  const int wr = w >> 1, wc = w & 1;
  const int fr = lane & 15, fq = lane >> 4;
  for (int kt = 0; kt < 768; kt += 64) {
    __syncthreads();
    #pragma unroll
    for (int t = 0; t < 2; ++t) {
      int g = t * 256 + tid;
      int row = g >> 3, s = g & 7;
      int sg = (s - row) & 7;
      const unsigned short* ga = Ab + (long long)(m0 + row) * lda + kt + sg * 8;
      __builtin_amdgcn_global_load_lds(
          (const __attribute__((address_space(1))) void*)ga,
          (__attribute__((address_space(3))) void*)(As + g * 16), 16, 0, 0);
    }
    #pragma unroll
    for (int t = 0; t < 2; ++t) {
      int g = t * 256 + tid;
      int row = g >> 3, s = g & 7;
      int sg = (s - row) & 7;
      const unsigned short* gb = Bb + (long long)(n0 + row) * ldb + kt + sg * 8;
      __builtin_amdgcn_global_load_lds(
          (const __attribute__((address_space(1))) void*)gb,
          (__attribute__((address_space(3))) void*)(Bs + g * 16), 16, 0, 0);
    }
    __syncthreads();
    #pragma unroll
    for (int kk = 0; kk < 2; ++kk) {
      short8 af[2], bfr[2];
      #pragma unroll
      for (int i = 0; i < 2; ++i) {
        int r = wr * 32 + i * 16 + fr;
        af[i] = *reinterpret_cast<const short8*>(As + r * 128 + (((kk * 4 + fq) + r) & 7) * 16);
      }
      #pragma unroll
      for (int j = 0; j < 2; ++j) {
        int r = wc * 32 + j * 16 + fr;
        bfr[j] = *reinterpret_cast<const short8*>(Bs + r * 128 + (((kk * 4 + fq) + r) & 7) * 16);
      }
      #pragma unroll
      for (int i = 0; i < 2; ++i)
        #pragma unroll
        for (int j = 0; j < 2; ++j)
          acc[i][j] = __builtin_amdgcn_mfma_f32_16x16x32_bf16(af[i], bfr[j], acc[i][j], 0, 0, 0);
    }
  }
}

// fused G1 (z=0) + W2 (z=1)
__global__ __launch_bounds__(256) void gemm_g1w2(
    const unsigned short* __restrict__ Wc2_bf, const unsigned short* __restrict__ prev_bf,
    const unsigned short* __restrict__ WqT_bf, const unsigned short* __restrict__ WkT_bf,
    const float* __restrict__ Wc, float* __restrict__ Mt_f,
    unsigned short* __restrict__ Mt_bf, unsigned short* __restrict__ W2_bf)
{
  __shared__ __align__(16) char As[64 * 128];
  __shared__ __align__(16) char Bs[64 * 128];
  int bx, by, bz;
  xcd_swz(bx, by, bz);
  const int m0 = by * 64, n0 = bx * 64;
  const unsigned short* A = bz ? WqT_bf : Wc2_bf;
  const unsigned short* B = bz ? WkT_bf : prev_bf;
  const int tid = threadIdx.x;
  f32x4 acc[2][2] = {};
  nt64_core(A, 768, B, 768, m0, n0, tid, acc, As, Bs);

  const int w = tid >> 6, lane = tid & 63;
  const int wr = w >> 1, wc = w & 1;
  const int fr = lane & 15, fq = lane >> 4;
  #pragma unroll
  for (int i = 0; i < 2; ++i)
    #pragma unroll
    for (int j = 0; j < 2; ++j)
      #pragma unroll
      for (int r = 0; r < 4; ++r) {
        int row = m0 + wr * 32 + i * 16 + fq * 4 + r;
        int col = n0 + wc * 32 + j * 16 + fr;
        float v = acc[i][j][r];
        if (bz == 0) {
          v += Wc[(long long)row * 1536 + col];
          Mt_f[(long long)row * 768 + col] = v;
          Mt_bf[(long long)row * 768 + col] = f2bf(v);
        } else {
          W2_bf[(long long)row * 768 + col] = f2bf(v);
        }
      }
}

// batched NT GEMM: MODE 2 plain, MODE 5 rank-1 epilogue
template <int MODE>
__global__ __launch_bounds__(256) void gemm_nt(
    const unsigned short* __restrict__ A, long long aStr,
    const unsigned short* __restrict__ B, long long bStr,
    unsigned short* __restrict__ Cbf, long long cStr,
    const float* __restrict__ aux, const float* __restrict__ aux2)
{
  __shared__ __align__(16) char As[64 * 128];
  __shared__ __align__(16) char Bs[64 * 128];
  int bx, by, bz;
  xcd_swz(bx, by, bz);
  const int b = bz;
  const int m0 = by * 64, n0 = bx * 64;
  const int tid = threadIdx.x;
  f32x4 acc[2][2] = {};
  nt64_core(A + (long long)b * aStr, 768, B + (long long)b * bStr, 768,
            m0, n0, tid, acc, As, Bs);

  const int w = tid >> 6, lane = tid & 63;
  const int wr = w >> 1, wc = w & 1;
  const int fr = lane & 15, fq = lane >> 4;
  #pragma unroll
  for (int i = 0; i < 2; ++i)
    #pragma unroll
    for (int j = 0; j < 2; ++j)
      #pragma unroll
      for (int r = 0; r < 4; ++r) {
        int row = m0 + wr * 32 + i * 16 + fq * 4 + r;
        int col = n0 + wc * 32 + j * 16 + fr;
        float v = acc[i][j][r];
        if constexpr (MODE == 5) v += aux[b * 768 + row] * aux2[col];
        Cbf[(long long)b * cStr + (long long)row * 768 + col] = f2bf(v);
      }
}

// ---------------- G5: 1 barrier per K-tile, counted vmcnt, 3 A-bufs ------------
__global__ __launch_bounds__(512, 1) void g5_pipe(
    const unsigned short* __restrict__ A,   // query_bf [8][2048][768]
    const unsigned short* __restrict__ B,   // Pt [8][768][768]
    float* __restrict__ C, const float* __restrict__ rowv)
{
  __shared__ __align__(16) char As[3][256 * 128];   // 3 x 32 KB
  __shared__ __align__(16) char Bs[2][192 * 128];   // 2 x 24 KB

  int lin = blockIdx.x + 4 * (blockIdx.y + 8 * blockIdx.z);
  int swz = (lin & 7) * 32 + (lin >> 3);
  int bz = swz >> 5;
  int rem = swz & 31;
  int by = rem >> 2, bx = rem & 3;

  const int b = bz;
  const int m0 = by * 256, n0 = bx * 192;
  const unsigned short* Ab = A + (long long)b * 1572864;
  const unsigned short* Bb = B + (long long)b * 589824;

  const int tid = threadIdx.x;
  const int w = tid >> 6, lane = tid & 63;
  const int wr = w >> 2, wn = w & 3;       // 2 M-waves x 4 N-waves
  const int fr = lane & 15, fq = lane >> 4;

  f32x4 acc[8][3] = {};

  auto stageA = [&](int buf, int kt) {
    #pragma unroll
    for (int s = 0; s < 4; ++s) {
      int g = s * 512 + tid;
      int row = g >> 3, slot = g & 7;
      int sg = (slot - row) & 7;
      const unsigned short* ga = Ab + (long long)(m0 + row) * 768 + kt + sg * 8;
      __builtin_amdgcn_global_load_lds(
          (const __attribute__((address_space(1))) void*)ga,
          (__attribute__((address_space(3))) void*)(&As[buf][0] + g * 16), 16, 0, 0);
    }
  };
  auto stageB = [&](int buf, int kt) {
    #pragma unroll
    for (int s = 0; s < 3; ++s) {
      int g = s * 512 + tid;
      int row = g >> 3, slot = g & 7;
      int sg = (slot - row) & 7;
      const unsigned short* gb = Bb + (long long)(n0 + row) * 768 + kt + sg * 8;
      __builtin_amdgcn_global_load_lds(
          (const __attribute__((address_space(1))) void*)gb,
          (__attribute__((address_space(3))) void*)(&Bs[buf][0] + g * 16), 16, 0, 0);
    }
  };

  // prologue: A(0), B(0), deep-prefetch A(1); wait A0+B0 (A1's 4 stay in flight)
  stageA(0, 0);
  stageB(0, 0);
  stageA(1, 64);
  asm volatile("s_waitcnt vmcnt(4)" ::: "memory");
  __builtin_amdgcn_s_barrier();

  for (int t = 0; t < 12; ++t) {
    const char* as = &As[t % 3][0];
    const char* bs = &Bs[t & 1][0];

    // issue next-tile loads first (they fly under the whole compute below)
    if (t < 11) stageB((t + 1) & 1, (t + 1) * 64);
    if (t < 10) stageA((t + 2) % 3, (t + 2) * 64);

    #pragma unroll
    for (int kk = 0; kk < 2; ++kk) {
      short8 a[8], bb[3];
      #pragma unroll
      for (int i = 0; i < 8; ++i) {
        int r = wr * 128 + i * 16 + fr;
        a[i] = *reinterpret_cast<const short8*>(as + r * 128 + (((kk * 4 + fq) + r) & 7) * 16);
      }
      #pragma unroll
      for (int j = 0; j < 3; ++j) {
        int r = wn * 48 + j * 16 + fr;
        bb[j] = *reinterpret_cast<const short8*>(bs + r * 128 + (((kk * 4 + fq) + r) & 7) * 16);
      }
      __builtin_amdgcn_s_setprio(1);
      #pragma unroll
      for (int i = 0; i < 8; ++i)
        #pragma unroll
        for (int j = 0; j < 3; ++j)
          acc[i][j] = __builtin_amdgcn_mfma_f32_16x16x32_bf16(a[i], bb[j], acc[i][j], 0, 0, 0);
      __builtin_amdgcn_s_setprio(0);
    }

    // boundary: counted wait. In flight: A(t+2) newest 4, then B(t+1), A(t+1).
    if (t < 10)       asm volatile("s_waitcnt vmcnt(4)" ::: "memory");
    else if (t == 10) asm volatile("s_waitcnt vmcnt(0)" ::: "memory");
    __builtin_amdgcn_s_barrier();
  }

  // epilogue
  const long long ob = (long long)b * 1572864;
  #pragma unroll
  for (int i = 0; i < 8; ++i)
    #pragma unroll
    for (int j = 0; j < 3; ++j)
      #pragma unroll
      for (int r = 0; r < 4; ++r) {
        int row = m0 + wr * 128 + i * 16 + fq * 4 + r;
        int col = n0 + wn * 48 + j * 16 + fr;
        C[ob + (long long)row * 768 + col] = acc[i][j][r] * SCALE + rowv[b * 768 + col];
      }
}

extern "C" void kernel_launch(void* const* d_in, const int* in_sizes, int n_in,
                              void* d_out, int out_size, void* d_ws, size_t ws_size,
                              hipStream_t stream)
{
  const float* query = (const float*)d_in[0];
  const float* key   = (const float*)d_in[1];
  const float* prev  = (const float*)d_in[3];
  const int*   mask  = (const int*)d_in[4];
  const float* Wq    = (const float*)d_in[5];
  const float* bq    = (const float*)d_in[6];
  const float* Wk    = (const float*)d_in[7];
  const float* bk    = (const float*)d_in[8];
  const float* Wc    = (const float*)d_in[11];
  const float* bc    = (const float*)d_in[12];
  float* out = (float*)d_out;

  char* p = (char*)d_ws;
  size_t off = 0;
  auto alloc = [&](size_t bytes) {
    char* r = p + off;
    off += (bytes + 255) & ~(size_t)255;
    return r;
  };
  unsigned short* query_bf = (unsigned short*)alloc(12582912ull * 2);
  unsigned short* keyzT_bf = (unsigned short*)alloc(4718592ull * 2);
  unsigned short* WqT_bf   = (unsigned short*)alloc(589824ull * 2);
  unsigned short* WkT_bf   = (unsigned short*)alloc(589824ull * 2);
  unsigned short* prev_bf  = (unsigned short*)alloc(589824ull * 2);
  unsigned short* Wc2_bf   = (unsigned short*)alloc(589824ull * 2);
  float*          Mt_f     = (float*)alloc(589824ull * 4);
  unsigned short* Mt_bf    = (unsigned short*)alloc(589824ull * 2);
  unsigned short* W2_bf    = (unsigned short*)alloc(589824ull * 2);
  unsigned short* Tt_bf    = (unsigned short*)alloc(4718592ull * 2);
  unsigned short* Pt_bf    = (unsigned short*)alloc(4718592ull * 2);
  float*          s1f      = (float*)alloc(6144ull * 4);
  float*          sm0f     = (float*)alloc(6144ull * 4);
  float*          uv       = (float*)alloc(768ull * 4);
  float*          w3v      = (float*)alloc(768ull * 4);
  float*          rowv     = (float*)alloc(6144ull * 4);
  (void)ws_size; (void)in_sizes; (void)n_in; (void)out_size;

  // prep
  k_cvt8<<<dim3(6144), dim3(256), 0, stream>>>(query, query_bf, 1572864);
  k_tcvt<<<dim3(12, 12, 10), dim3(256), 0, stream>>>(Wq, Wk, key, mask,
                                                     WqT_bf, WkT_bf, keyzT_bf);
  k_prep<<<dim3(1152), dim3(256), 0, stream>>>(prev, Wc, prev_bf, Wc2_bf);

  // G1 + W2 fused
  gemm_g1w2<<<dim3(12, 12, 2), dim3(256), 0, stream>>>(
      Wc2_bf, prev_bf, WqT_bf, WkT_bf, Wc, Mt_f, Mt_bf, W2_bf);
  // u, w3, s1, sm0
  k_sums<<<dim3(1920), dim3(256), 0, stream>>>(WqT_bf, WkT_bf, bk, bq, Mt_f, mask,
                                               uv, w3v, s1f, sm0f);
  // G3': Tt[b] = NT(Mt, keyzT[b])
  gemm_nt<2><<<dim3(12, 12, 8), dim3(256), 0, stream>>>(
      Mt_bf, 0ll, keyzT_bf, 589824ll, Tt_bf, 589824ll,
      (const float*)nullptr, (const float*)nullptr);
  // G4': Pt[b] = NT(Tt[b], W2) + s1[b][m]*u[n]
  gemm_nt<5><<<dim3(12, 12, 8), dim3(256), 0, stream>>>(
      Tt_bf, 589824ll, W2_bf, 0ll, Pt_bf, 589824ll, s1f, uv);
  // row constants
  k_row<<<dim3(1536), dim3(256), 0, stream>>>(Tt_bf, w3v, s1f, sm0f, bq, bk, bc, rowv);
  // G5: 1-barrier counted pipeline
  g5_pipe<<<dim3(4, 8, 8), dim3(512), 0, stream>>>(query_bf, Pt_bf, out, rowv);
}